// Round 4
// baseline (10205.437 us; speedup 1.0000x reference)
//
#include <hip/hip_runtime.h>
#include <cmath>

#define BB 64
#define TT 250
#define CC 1024
#define UU 512
#define GG 1536   // 3U
#define NB 256    // scan grid: 1 block/CU (152 KB LDS), exactly co-resident

// workspace layout (float offsets)
#define O_XGF 0             // also carries y_f[t][u][b] after consumption (deferred store)
#define O_XGB 24576000      // T*B*G = 250*64*1536
#define O_UT  49152000      // 2*512*3*512
#define O_HT  50724864      // 2 bufs * 2 dirs * [512 u][64 b]
#define O_MF  50855936      // T*B
#define O_BAR 50871936      // 256 uint per-block arrival slots (per-dir barrier)

__global__ __launch_bounds__(256) void prep_kernel(
    const unsigned char* __restrict__ mraw,
    float* __restrict__ ut, float* __restrict__ mf, float* __restrict__ ht,
    unsigned int* __restrict__ bar,
    const float* __restrict__ Uf, const float* __restrict__ Ub)
{
  int idx = blockIdx.x * 256 + threadIdx.x;
  // transpose U into ut[(d*512+u)*3 + g][k] = U_d[k][g*512+u]
  if (idx < 2*512*3*512) {
    int k = idx & 511;
    int r = idx >> 9;
    int g = r % 3;
    int rest = r / 3;        // d*512 + u
    int u = rest & 511;
    int dd = rest >> 9;
    const float* Um = dd ? Ub : Uf;
    ut[idx] = Um[k*GG + (g << 9) + u];
  }
  if (idx < 131072) ht[idx] = 0.0f;      // zero both h ping-pong buffers
  if (idx < 256) bar[idx] = 0u;          // zero arrival slots (every call: replays!)
  // mask -> float [t][b]; detect bool8 vs int32 storage via byte 1 (mask[0][1] true)
  if (idx < BB*TT) {
    int b = idx / TT, t = idx - b*TT;
    bool bytefmt = (mraw[1] == 1);
    bool mv = bytefmt ? (mraw[idx] != 0) : (((const int*)mraw)[idx] != 0);
    mf[t*BB + b] = mv ? 1.0f : 0.0f;
  }
}

// C = A(16000x1024) * W(1024x1536) + bias, both directions; out XG[t][b][g].
// Bank-conflict-fixed n-mapping: thread covers cols {tn..tn+3, tn+64..tn+67}, tn=(tid&15)*4.
__global__ __launch_bounds__(256) void gemm_xg(
    const float* __restrict__ A,
    const float* __restrict__ Wf, const float* __restrict__ Wb,
    const float* __restrict__ bf, const float* __restrict__ bb,
    float* __restrict__ xgf, float* __restrict__ xgb)
{
  __shared__ float As[16][132];
  __shared__ float Bs[16][128];
  const int tid = threadIdx.x;
  const int m0 = blockIdx.x * 128;
  const int n0 = blockIdx.y * 128;
  const int d  = (n0 >= GG) ? 1 : 0;
  const int nl0 = n0 - d*GG;
  const float* Wm  = d ? Wb : Wf;
  const float* bias = d ? bb : bf;
  float* xg = d ? xgb : xgf;
  const int tm = (tid >> 4) << 3;
  const int tn = (tid & 15) << 2;        // 0,4,...,60: 2-way (free) on b128 reads
  float acc[8][8];
  #pragma unroll
  for (int i = 0; i < 8; i++)
    #pragma unroll
    for (int j = 0; j < 8; j++) acc[i][j] = 0.0f;
  for (int k0 = 0; k0 < CC; k0 += 16) {
    #pragma unroll
    for (int j = 0; j < 2; j++) {
      int f = tid*2 + j;
      int r = f >> 2;
      int kk = (f & 3) << 2;
      float4 av = *(const float4*)(A + (size_t)(m0+r)*CC + k0 + kk);
      As[kk+0][r] = av.x; As[kk+1][r] = av.y; As[kk+2][r] = av.z; As[kk+3][r] = av.w;
    }
    #pragma unroll
    for (int j = 0; j < 2; j++) {
      int f = tid*2 + j;
      int kr = f >> 5;
      int nn = (f & 31) << 2;
      *(float4*)&Bs[kr][nn] = *(const float4*)(Wm + (size_t)(k0+kr)*GG + nl0 + nn);
    }
    __syncthreads();
    #pragma unroll
    for (int k = 0; k < 16; k++) {
      float4 a0 = *(const float4*)&As[k][tm];
      float4 a1 = *(const float4*)&As[k][tm+4];
      float4 b0 = *(const float4*)&Bs[k][tn];
      float4 b1 = *(const float4*)&Bs[k][tn+64];
      float av[8] = {a0.x,a0.y,a0.z,a0.w,a1.x,a1.y,a1.z,a1.w};
      float bv[8] = {b0.x,b0.y,b0.z,b0.w,b1.x,b1.y,b1.z,b1.w};
      #pragma unroll
      for (int i = 0; i < 8; i++)
        #pragma unroll
        for (int jj = 0; jj < 8; jj++) acc[i][jj] = fmaf(av[i], bv[jj], acc[i][jj]);
    }
    __syncthreads();
  }
  float bva[4], bvb[4];
  #pragma unroll
  for (int j = 0; j < 4; j++) { bva[j] = bias[nl0+tn+j]; bvb[j] = bias[nl0+tn+64+j]; }
  #pragma unroll
  for (int i = 0; i < 8; i++) {
    int m = m0 + tm + i;
    int b = m / TT;
    int t = m - b*TT;
    float* o = xg + (size_t)(t*BB + b)*GG + nl0;
    float4 o0 = {acc[i][0]+bva[0], acc[i][1]+bva[1], acc[i][2]+bva[2], acc[i][3]+bva[3]};
    float4 o1 = {acc[i][4]+bvb[0], acc[i][5]+bvb[1], acc[i][6]+bvb[2], acc[i][7]+bvb[3]};
    *(float4*)(o+tn) = o0; *(float4*)(o+tn+64) = o1;
  }
}

// Persistent scan. 256 blocks: d=bid>>7, 4 u per block (wave=u, lane=b).
// U-slice in LDS (24 KB, loaded once); h staged to LDS per step in 4 pipelined
// chunks; y stored DEFERRED one step into the dead xg[t] slot (coalesced
// [t][u][b]); per-direction distributed barrier.
__global__ __launch_bounds__(256, 1) void gru_scan(
    const float* __restrict__ xgf, const float* __restrict__ xgb,
    float* __restrict__ xgfw, float* __restrict__ xgbw,
    const float* __restrict__ ut, const float* __restrict__ bf,
    const float* __restrict__ bb, const float* __restrict__ mf,
    float* __restrict__ ht, unsigned int* __restrict__ bar,
    float* __restrict__ out)
{
  extern __shared__ float lds[];
  float* hbuf = lds;                 // 32768 floats: h[512 k][64 b]
  float* us   = lds + 32768;         // 6144 floats: U slice [4 wv][3 g][512 k]
  const int tid  = threadIdx.x;
  const int lane = tid & 63;               // batch b
  const int bid  = blockIdx.x;
  const int d    = bid >> 7;
  const int wv   = __builtin_amdgcn_readfirstlane(tid >> 6);
  const int u    = __builtin_amdgcn_readfirstlane(((bid & 127) << 2) | wv);
  // load U slice (block's 4 u rows = 6144 contiguous floats in ut)
  {
    const float4* usrc = (const float4*)(ut + (size_t)(((d << 9) + ((bid & 127) << 2)) * 3) * 512);
    float4* ud = (float4*)us;
    #pragma unroll
    for (int j = 0; j < 6; j++) ud[j*256 + tid] = usrc[j*256 + tid];
  }
  const float* uzL = us + (size_t)(wv*3) * 512;
  const float* urL = uzL + 512;
  const float* uhL = uzL + 1024;
  const float* bias = (d ? bb : bf) + GG;
  const float b1z = bias[u], b1r = bias[512+u], b1h = bias[1024+u];
  const float* xgr = d ? xgb : xgf;
  float* ywr = d ? xgbw : xgfw;
  float hprev = 0.0f, ysave = 0.0f;
  int tprev = 0;

  for (int s = 0; s < TT; s++) {
    const int t = d ? (TT-1-s) : s;
    // prefetch xg(t) + mask BEFORE barrier (latency hides under spin; also
    // required ordering for the deferred y overwrite of slot t-1)
    const float* xgp = xgr + (size_t)t*98304 + (size_t)lane*GG + u;
    float xz = xgp[0];
    float xr = xgp[512];
    float xh = xgp[1024];
    float m  = mf[t*BB + lane];
    if (s) {
      __syncthreads();   // step s-1 done: h stores issued, hbuf free
      if (tid == 0)
        __hip_atomic_store(&bar[bid], (unsigned)s, __ATOMIC_RELEASE, __HIP_MEMORY_SCOPE_AGENT);
      if (tid < 64) {    // wave 0 polls own direction's 128 slots, 2/lane
        const int i0 = (d << 7) | (lane << 1);
        while (true) {
          unsigned v0 = __hip_atomic_load(&bar[i0+0], __ATOMIC_RELAXED, __HIP_MEMORY_SCOPE_AGENT);
          unsigned v1 = __hip_atomic_load(&bar[i0+1], __ATOMIC_RELAXED, __HIP_MEMORY_SCOPE_AGENT);
          if (__all((v0 >= (unsigned)s) && (v1 >= (unsigned)s))) break;
          __builtin_amdgcn_s_sleep(1);
        }
      }
      __syncthreads();
      __builtin_amdgcn_fence(__ATOMIC_ACQUIRE, "agent");
      // deferred y(t_prev) -> dead xg slot, coalesced [t][u][b]
      ywr[(size_t)tprev*98304 + ((size_t)u << 6) + lane] = ysave;
    }
    // stage h chunk 0 (32 KB)
    const float* hin = ht + (((s & 1) << 1 | d) << 15);
    {
      float4 st[8];
      const float4* sp = (const float4*)hin;
      #pragma unroll
      for (int j = 0; j < 8; j++) st[j] = sp[j*256 + tid];
      float4* dp = (float4*)hbuf;
      #pragma unroll
      for (int j = 0; j < 8; j++) dp[j*256 + tid] = st[j];
    }
    __syncthreads();
    float az0=0, az1=0, ar0=0, ar1=0, ah0=0, ah1=0;
    for (int c = 0; c < 4; c++) {
      float4 stg[8];
      if (c < 3) {       // issue next-chunk global loads early
        const float4* sp = (const float4*)(hin + (c+1)*8192);
        #pragma unroll
        for (int j = 0; j < 8; j++) stg[j] = sp[j*256 + tid];
      }
      const int k0 = c << 7;
      #pragma unroll 8
      for (int kq = 0; kq < 128; kq += 4) {
        const int k = k0 + kq;
        float4 z4 = *(const float4*)(uzL + k);   // uniform ds_read_b128 (broadcast)
        float4 r4 = *(const float4*)(urL + k);
        float4 h4 = *(const float4*)(uhL + k);
        float a0 = hbuf[((k+0) << 6) | lane];    // conflict-free (2 lanes/bank)
        float a1 = hbuf[((k+1) << 6) | lane];
        float a2 = hbuf[((k+2) << 6) | lane];
        float a3 = hbuf[((k+3) << 6) | lane];
        az0 = fmaf(a0, z4.x, az0); az1 = fmaf(a1, z4.y, az1);
        az0 = fmaf(a2, z4.z, az0); az1 = fmaf(a3, z4.w, az1);
        ar0 = fmaf(a0, r4.x, ar0); ar1 = fmaf(a1, r4.y, ar1);
        ar0 = fmaf(a2, r4.z, ar0); ar1 = fmaf(a3, r4.w, ar1);
        ah0 = fmaf(a0, h4.x, ah0); ah1 = fmaf(a1, h4.y, ah1);
        ah0 = fmaf(a2, h4.z, ah0); ah1 = fmaf(a3, h4.w, ah1);
      }
      if (c < 3) {       // write staged chunk, publish to all waves
        float4* dp = (float4*)(hbuf + (c+1)*8192);
        #pragma unroll
        for (int j = 0; j < 8; j++) dp[j*256 + tid] = stg[j];
        __syncthreads();
      }
    }
    float az = az0+az1, ar = ar0+ar1, ah = ah0+ah1;
    float z  = 1.0f / (1.0f + expf(-(xz + az + b1z)));
    float r  = 1.0f / (1.0f + expf(-(xr + ar + b1r)));
    float cc = tanhf(xh + r * (ah + b1h));
    float hn = z*hprev + (1.0f - z)*cc;
    hn = (m != 0.0f) ? hn : hprev;
    hprev = hn; ysave = hn; tprev = t;
    float* hout = ht + ((((s & 1) ^ 1) << 1 | d) << 15);
    hout[(u << 6) | lane] = hn;    // [u][b], 256 B/wave coalesced
  }
  // final barrier orders last y overwrite vs other blocks' xg reads
  __syncthreads();
  if (tid == 0)
    __hip_atomic_store(&bar[bid], (unsigned)TT, __ATOMIC_RELEASE, __HIP_MEMORY_SCOPE_AGENT);
  if (tid < 64) {
    const int i0 = (d << 7) | (lane << 1);
    while (true) {
      unsigned v0 = __hip_atomic_load(&bar[i0+0], __ATOMIC_RELAXED, __HIP_MEMORY_SCOPE_AGENT);
      unsigned v1 = __hip_atomic_load(&bar[i0+1], __ATOMIC_RELAXED, __HIP_MEMORY_SCOPE_AGENT);
      if (__all((v0 >= (unsigned)TT) && (v1 >= (unsigned)TT))) break;
      __builtin_amdgcn_s_sleep(1);
    }
  }
  __syncthreads();
  ywr[(size_t)tprev*98304 + ((size_t)u << 6) + lane] = ysave;
  out[16384000ull + ((size_t)lane << 10) + (d << 9) + u] = hprev;  // state (scatter, once)
}

// out[b][t][d*512+u] <- y stored as [t][u][b] inside xg slots
__global__ __launch_bounds__(256) void y_transpose(
    const float* __restrict__ xgf, const float* __restrict__ xgb,
    float* __restrict__ out)
{
  __shared__ float tile[64][65];
  const int t  = blockIdx.x;
  const int ch = blockIdx.y;           // d*8 + uc
  const int d  = ch >> 3, uc = ch & 7;
  const float* src = (d ? xgb : xgf) + (size_t)t*98304 + (size_t)uc*4096;
  const int lane = threadIdx.x & 63, w = threadIdx.x >> 6;
  #pragma unroll
  for (int j = 0; j < 16; j++) {
    int r = j*4 + w;                   // u' within chunk
    tile[r][lane] = src[r*64 + lane];  // coalesced read (lane=b)
  }
  __syncthreads();
  #pragma unroll
  for (int j = 0; j < 16; j++) {
    int b = j*4 + w;
    out[((size_t)b*TT + t)*1024 + (d << 9) + (uc << 6) + lane] = tile[lane][b];
  }
}

extern "C" void kernel_launch(void* const* d_in, const int* in_sizes, int n_in,
                              void* d_out, int out_size, void* d_ws, size_t ws_size,
                              hipStream_t stream) {
  const float* X  = (const float*)d_in[0];
  const unsigned char* Mk = (const unsigned char*)d_in[1];
  const float* Wf = (const float*)d_in[2];
  const float* Uf = (const float*)d_in[3];
  const float* bf = (const float*)d_in[4];
  const float* Wb = (const float*)d_in[5];
  const float* Ub = (const float*)d_in[6];
  const float* bb = (const float*)d_in[7];
  float* out = (float*)d_out;
  float* ws  = (float*)d_ws;
  float* xgf = ws + O_XGF;
  float* xgb = ws + O_XGB;
  float* ut  = ws + O_UT;
  float* ht  = ws + O_HT;
  float* mf  = ws + O_MF;
  unsigned int* bar = (unsigned int*)(ws + O_BAR);

  hipFuncSetAttribute((const void*)gru_scan,
                      hipFuncAttributeMaxDynamicSharedMemorySize, 155648);

  prep_kernel<<<dim3(6144), dim3(256), 0, stream>>>(Mk, ut, mf, ht, bar, Uf, Ub);
  gemm_xg<<<dim3(125, 24), dim3(256), 0, stream>>>(X, Wf, Wb, bf, bb, xgf, xgb);
  gru_scan<<<dim3(NB), dim3(256), 155648, stream>>>(xgf, xgb, xgf, xgb, ut, bf, bb, mf, ht, bar, out);
  y_transpose<<<dim3(TT, 16), dim3(256), 0, stream>>>(xgf, xgb, out);
}

// Round 5
// 6550.726 us; speedup vs baseline: 1.5579x; 1.5579x over previous
//
#include <hip/hip_runtime.h>
#include <cmath>

#define BB 64
#define TT 250
#define CC 1024
#define UU 512
#define GG 1536   // 3U
#define NB 256    // scan grid: 1 block/CU (152 KB LDS), exactly co-resident

typedef unsigned long long u64t;

// workspace layout (float offsets)
#define O_XGF 0             // also carries y_f[t][u][b] after consumption (deferred store)
#define O_XGB 24576000      // T*B*G = 250*64*1536
#define O_UT  49152000      // 2*512*3*512
#define O_HT  50724864      // 2 bufs * 2 dirs * [512 u][64 b]
#define O_MF  50855936      // T*B
#define O_BAR 50871936      // 256 uint per-block arrival slots (per-dir barrier)

__global__ __launch_bounds__(256) void prep_kernel(
    const unsigned char* __restrict__ mraw,
    float* __restrict__ ut, float* __restrict__ mf, float* __restrict__ ht,
    unsigned int* __restrict__ bar,
    const float* __restrict__ Uf, const float* __restrict__ Ub)
{
  int idx = blockIdx.x * 256 + threadIdx.x;
  // transpose U into ut[(d*512+u)*3 + g][k] = U_d[k][g*512+u]
  if (idx < 2*512*3*512) {
    int k = idx & 511;
    int r = idx >> 9;
    int g = r % 3;
    int rest = r / 3;        // d*512 + u
    int u = rest & 511;
    int dd = rest >> 9;
    const float* Um = dd ? Ub : Uf;
    ut[idx] = Um[k*GG + (g << 9) + u];
  }
  if (idx < 131072) ht[idx] = 0.0f;      // zero both h ping-pong buffers
  if (idx < 256) bar[idx] = 0u;          // zero arrival slots (every call: replays!)
  // mask -> float [t][b]; detect bool8 vs int32 storage via byte 1 (mask[0][1] true)
  if (idx < BB*TT) {
    int b = idx / TT, t = idx - b*TT;
    bool bytefmt = (mraw[1] == 1);
    bool mv = bytefmt ? (mraw[idx] != 0) : (((const int*)mraw)[idx] != 0);
    mf[t*BB + b] = mv ? 1.0f : 0.0f;
  }
}

// C = A(16000x1024) * W(1024x1536) + bias, both directions; out XG[t][b][g].
__global__ __launch_bounds__(256) void gemm_xg(
    const float* __restrict__ A,
    const float* __restrict__ Wf, const float* __restrict__ Wb,
    const float* __restrict__ bf, const float* __restrict__ bb,
    float* __restrict__ xgf, float* __restrict__ xgb)
{
  __shared__ float As[16][132];
  __shared__ float Bs[16][128];
  const int tid = threadIdx.x;
  const int m0 = blockIdx.x * 128;
  const int n0 = blockIdx.y * 128;
  const int d  = (n0 >= GG) ? 1 : 0;
  const int nl0 = n0 - d*GG;
  const float* Wm  = d ? Wb : Wf;
  const float* bias = d ? bb : bf;
  float* xg = d ? xgb : xgf;
  const int tm = (tid >> 4) << 3;
  const int tn = (tid & 15) << 2;        // cols {tn..tn+3, tn+64..tn+67}: 2-way (free)
  float acc[8][8];
  #pragma unroll
  for (int i = 0; i < 8; i++)
    #pragma unroll
    for (int j = 0; j < 8; j++) acc[i][j] = 0.0f;
  for (int k0 = 0; k0 < CC; k0 += 16) {
    #pragma unroll
    for (int j = 0; j < 2; j++) {
      int f = tid*2 + j;
      int r = f >> 2;
      int kk = (f & 3) << 2;
      float4 av = *(const float4*)(A + (size_t)(m0+r)*CC + k0 + kk);
      As[kk+0][r] = av.x; As[kk+1][r] = av.y; As[kk+2][r] = av.z; As[kk+3][r] = av.w;
    }
    #pragma unroll
    for (int j = 0; j < 2; j++) {
      int f = tid*2 + j;
      int kr = f >> 5;
      int nn = (f & 31) << 2;
      *(float4*)&Bs[kr][nn] = *(const float4*)(Wm + (size_t)(k0+kr)*GG + nl0 + nn);
    }
    __syncthreads();
    #pragma unroll
    for (int k = 0; k < 16; k++) {
      float4 a0 = *(const float4*)&As[k][tm];
      float4 a1 = *(const float4*)&As[k][tm+4];
      float4 b0 = *(const float4*)&Bs[k][tn];
      float4 b1 = *(const float4*)&Bs[k][tn+64];
      float av[8] = {a0.x,a0.y,a0.z,a0.w,a1.x,a1.y,a1.z,a1.w};
      float bv[8] = {b0.x,b0.y,b0.z,b0.w,b1.x,b1.y,b1.z,b1.w};
      #pragma unroll
      for (int i = 0; i < 8; i++)
        #pragma unroll
        for (int jj = 0; jj < 8; jj++) acc[i][jj] = fmaf(av[i], bv[jj], acc[i][jj]);
    }
    __syncthreads();
  }
  float bva[4], bvb[4];
  #pragma unroll
  for (int j = 0; j < 4; j++) { bva[j] = bias[nl0+tn+j]; bvb[j] = bias[nl0+tn+64+j]; }
  #pragma unroll
  for (int i = 0; i < 8; i++) {
    int m = m0 + tm + i;
    int b = m / TT;
    int t = m - b*TT;
    float* o = xg + (size_t)(t*BB + b)*GG + nl0;
    float4 o0 = {acc[i][0]+bva[0], acc[i][1]+bva[1], acc[i][2]+bva[2], acc[i][3]+bva[3]};
    float4 o1 = {acc[i][4]+bvb[0], acc[i][5]+bvb[1], acc[i][6]+bvb[2], acc[i][7]+bvb[3]};
    *(float4*)(o+tn) = o0; *(float4*)(o+tn+64) = o1;
  }
}

// Persistent scan, FENCE-FREE barrier: h published via sc0sc1 write-through
// (relaxed agent atomic stores), staged via sc0sc1 L2-bypass loads (relaxed
// agent atomic loads). Flag ordering: compiler's vmcnt(0) drain before
// s_barrier guarantees all waves' h-stores reached L3 before tid0's flag store.
// No buffer_wbl2 / buffer_inv -> L2 stays warm for xg/mf.
__global__ __launch_bounds__(256, 1) void gru_scan(
    const float* __restrict__ xgf, const float* __restrict__ xgb,
    float* __restrict__ xgfw, float* __restrict__ xgbw,
    const float* __restrict__ ut, const float* __restrict__ bf,
    const float* __restrict__ bb, const float* __restrict__ mf,
    float* __restrict__ ht, unsigned int* __restrict__ bar,
    float* __restrict__ out)
{
  extern __shared__ float lds[];
  float* hbuf = lds;                 // 32768 floats: h[512 k][64 b]
  float* us   = lds + 32768;         // 6144 floats: U slice [4 wv][3 g][512 k]
  const int tid  = threadIdx.x;
  const int lane = tid & 63;               // batch b
  const int bid  = blockIdx.x;
  const int d    = bid >> 7;
  const int wv   = __builtin_amdgcn_readfirstlane(tid >> 6);
  const int u    = __builtin_amdgcn_readfirstlane(((bid & 127) << 2) | wv);
  // load U slice (block's 4 u rows = 6144 contiguous floats in ut)
  {
    const float4* usrc = (const float4*)(ut + (size_t)(((d << 9) + ((bid & 127) << 2)) * 3) * 512);
    float4* ud = (float4*)us;
    #pragma unroll
    for (int j = 0; j < 6; j++) ud[j*256 + tid] = usrc[j*256 + tid];
  }
  const float* uzL = us + (size_t)(wv*3) * 512;
  const float* urL = uzL + 512;
  const float* uhL = uzL + 1024;
  const float* bias = (d ? bb : bf) + GG;
  const float b1z = bias[u], b1r = bias[512+u], b1h = bias[1024+u];
  const float* xgr = d ? xgb : xgf;
  float* ywr = d ? xgbw : xgfw;
  float hprev = 0.0f, ysave = 0.0f;
  int tprev = 0;

  for (int s = 0; s < TT; s++) {
    const int t = d ? (TT-1-s) : s;
    if (s) {
      __syncthreads();   // step s-1 done; compiler drains vmcnt for ALL waves here
      if (tid == 0) {
        asm volatile("s_waitcnt vmcnt(0)" ::: "memory");  // belt & suspenders
        __hip_atomic_store(&bar[bid], (unsigned)s, __ATOMIC_RELAXED, __HIP_MEMORY_SCOPE_AGENT);
      }
    }
    // prefetch xg(t)+mask AFTER flag store: HBM/L2 latency overlaps the spin
    const float* xgp = xgr + (size_t)t*98304 + (size_t)lane*GG + u;
    float xz = xgp[0];
    float xr = xgp[512];
    float xh = xgp[1024];
    float m  = mf[t*BB + lane];
    if (s) {
      if (tid < 64) {    // wave 0 polls own direction's 128 slots, 2/lane
        const int i0 = (d << 7) | (lane << 1);
        while (true) {
          unsigned v0 = __hip_atomic_load(&bar[i0+0], __ATOMIC_RELAXED, __HIP_MEMORY_SCOPE_AGENT);
          unsigned v1 = __hip_atomic_load(&bar[i0+1], __ATOMIC_RELAXED, __HIP_MEMORY_SCOPE_AGENT);
          if (__all((v0 >= (unsigned)s) && (v1 >= (unsigned)s))) break;
          __builtin_amdgcn_s_sleep(1);
        }
      }
      __syncthreads();
      // deferred y(t_prev) -> dead xg slot, coalesced [t][u][b] (plain store)
      ywr[(size_t)tprev*98304 + ((size_t)u << 6) + lane] = ysave;
    }
    // stage h[512][64] via L2-bypass loads, 4 pipelined 32 KB chunks
    const float* hin = ht + (((s & 1) << 1 | d) << 15);
    {
      u64t st[16];
      u64t* sp = (u64t*)hin;
      #pragma unroll
      for (int j = 0; j < 16; j++)
        st[j] = __hip_atomic_load(&sp[j*256 + tid], __ATOMIC_RELAXED, __HIP_MEMORY_SCOPE_AGENT);
      u64t* dp = (u64t*)hbuf;
      #pragma unroll
      for (int j = 0; j < 16; j++) dp[j*256 + tid] = st[j];
    }
    __syncthreads();
    float az0=0, az1=0, ar0=0, ar1=0, ah0=0, ah1=0;
    for (int c = 0; c < 4; c++) {
      u64t stg[16];
      if (c < 3) {       // issue next-chunk L2-bypass loads early
        u64t* sp = (u64t*)(hin + (c+1)*8192);
        #pragma unroll
        for (int j = 0; j < 16; j++)
          stg[j] = __hip_atomic_load(&sp[j*256 + tid], __ATOMIC_RELAXED, __HIP_MEMORY_SCOPE_AGENT);
      }
      const int k0 = c << 7;
      #pragma unroll 8
      for (int kq = 0; kq < 128; kq += 4) {
        const int k = k0 + kq;
        float4 z4 = *(const float4*)(uzL + k);   // uniform ds_read_b128 (broadcast)
        float4 r4 = *(const float4*)(urL + k);
        float4 h4 = *(const float4*)(uhL + k);
        float a0 = hbuf[((k+0) << 6) | lane];    // conflict-free (2 lanes/bank)
        float a1 = hbuf[((k+1) << 6) | lane];
        float a2 = hbuf[((k+2) << 6) | lane];
        float a3 = hbuf[((k+3) << 6) | lane];
        az0 = fmaf(a0, z4.x, az0); az1 = fmaf(a1, z4.y, az1);
        az0 = fmaf(a2, z4.z, az0); az1 = fmaf(a3, z4.w, az1);
        ar0 = fmaf(a0, r4.x, ar0); ar1 = fmaf(a1, r4.y, ar1);
        ar0 = fmaf(a2, r4.z, ar0); ar1 = fmaf(a3, r4.w, ar1);
        ah0 = fmaf(a0, h4.x, ah0); ah1 = fmaf(a1, h4.y, ah1);
        ah0 = fmaf(a2, h4.z, ah0); ah1 = fmaf(a3, h4.w, ah1);
      }
      if (c < 3) {       // write staged chunk, publish to all waves
        u64t* dp = (u64t*)(hbuf + (c+1)*8192);
        #pragma unroll
        for (int j = 0; j < 16; j++) dp[j*256 + tid] = stg[j];
        __syncthreads();
      }
    }
    float az = az0+az1, ar = ar0+ar1, ah = ah0+ah1;
    float z  = 1.0f / (1.0f + expf(-(xz + az + b1z)));
    float r  = 1.0f / (1.0f + expf(-(xr + ar + b1r)));
    float cc = tanhf(xh + r * (ah + b1h));
    float hn = z*hprev + (1.0f - z)*cc;
    hn = (m != 0.0f) ? hn : hprev;
    hprev = hn; ysave = hn; tprev = t;
    // publish h via write-through (no dirty L2 line): relaxed agent atomic
    float* hout = ht + ((((s & 1) ^ 1) << 1 | d) << 15);
    __hip_atomic_store(&hout[(u << 6) | lane], hn, __ATOMIC_RELAXED, __HIP_MEMORY_SCOPE_AGENT);
  }
  // final barrier orders last y overwrite vs other blocks' xg reads
  __syncthreads();
  if (tid == 0) {
    asm volatile("s_waitcnt vmcnt(0)" ::: "memory");
    __hip_atomic_store(&bar[bid], (unsigned)TT, __ATOMIC_RELAXED, __HIP_MEMORY_SCOPE_AGENT);
  }
  if (tid < 64) {
    const int i0 = (d << 7) | (lane << 1);
    while (true) {
      unsigned v0 = __hip_atomic_load(&bar[i0+0], __ATOMIC_RELAXED, __HIP_MEMORY_SCOPE_AGENT);
      unsigned v1 = __hip_atomic_load(&bar[i0+1], __ATOMIC_RELAXED, __HIP_MEMORY_SCOPE_AGENT);
      if (__all((v0 >= (unsigned)TT) && (v1 >= (unsigned)TT))) break;
      __builtin_amdgcn_s_sleep(1);
    }
  }
  __syncthreads();
  ywr[(size_t)tprev*98304 + ((size_t)u << 6) + lane] = ysave;
  out[16384000ull + ((size_t)lane << 10) + (d << 9) + u] = hprev;  // state (scatter, once)
}

// out[b][t][d*512+u] <- y stored as [t][u][b] inside xg slots
__global__ __launch_bounds__(256) void y_transpose(
    const float* __restrict__ xgf, const float* __restrict__ xgb,
    float* __restrict__ out)
{
  __shared__ float tile[64][65];
  const int t  = blockIdx.x;
  const int ch = blockIdx.y;           // d*8 + uc
  const int d  = ch >> 3, uc = ch & 7;
  const float* src = (d ? xgb : xgf) + (size_t)t*98304 + (size_t)uc*4096;
  const int lane = threadIdx.x & 63, w = threadIdx.x >> 6;
  #pragma unroll
  for (int j = 0; j < 16; j++) {
    int r = j*4 + w;                   // u' within chunk
    tile[r][lane] = src[r*64 + lane];  // coalesced read (lane=b)
  }
  __syncthreads();
  #pragma unroll
  for (int j = 0; j < 16; j++) {
    int b = j*4 + w;
    out[((size_t)b*TT + t)*1024 + (d << 9) + (uc << 6) + lane] = tile[lane][b];
  }
}

extern "C" void kernel_launch(void* const* d_in, const int* in_sizes, int n_in,
                              void* d_out, int out_size, void* d_ws, size_t ws_size,
                              hipStream_t stream) {
  const float* X  = (const float*)d_in[0];
  const unsigned char* Mk = (const unsigned char*)d_in[1];
  const float* Wf = (const float*)d_in[2];
  const float* Uf = (const float*)d_in[3];
  const float* bf = (const float*)d_in[4];
  const float* Wb = (const float*)d_in[5];
  const float* Ub = (const float*)d_in[6];
  const float* bb = (const float*)d_in[7];
  float* out = (float*)d_out;
  float* ws  = (float*)d_ws;
  float* xgf = ws + O_XGF;
  float* xgb = ws + O_XGB;
  float* ut  = ws + O_UT;
  float* ht  = ws + O_HT;
  float* mf  = ws + O_MF;
  unsigned int* bar = (unsigned int*)(ws + O_BAR);

  hipFuncSetAttribute((const void*)gru_scan,
                      hipFuncAttributeMaxDynamicSharedMemorySize, 155648);

  prep_kernel<<<dim3(6144), dim3(256), 0, stream>>>(Mk, ut, mf, ht, bar, Uf, Ub);
  gemm_xg<<<dim3(125, 24), dim3(256), 0, stream>>>(X, Wf, Wb, bf, bb, xgf, xgb);
  gru_scan<<<dim3(NB), dim3(256), 155648, stream>>>(xgf, xgb, xgf, xgb, ut, bf, bb, mf, ht, bar, out);
  y_transpose<<<dim3(TT, 16), dim3(256), 0, stream>>>(xgf, xgb, out);
}

// Round 6
// 6139.603 us; speedup vs baseline: 1.6622x; 1.0670x over previous
//
#include <hip/hip_runtime.h>
#include <cmath>

#define BB 64
#define TT 250
#define CC 1024
#define UU 512
#define GG 1536   // 3U
#define NB 256    // scan grid: 1 block/CU (152 KB LDS), exactly co-resident

typedef unsigned long long u64t;

// workspace layout (float offsets)
#define O_XGF 0             // [t][g][u][b]; g=0 region later overwritten by y_f[t][u][b]
#define O_XGB 24576000      // T*B*G = 250*64*1536
#define O_UT  49152000      // 2*512*3*512
#define O_HT  50724864      // 2 bufs * 2 dirs * [512 u][64 b]
#define O_MF  50855936      // T*B
#define O_BAR 50871936      // 256 uint per-block arrival slots (per-dir barrier)

__global__ __launch_bounds__(256) void prep_kernel(
    const unsigned char* __restrict__ mraw,
    float* __restrict__ ut, float* __restrict__ mf, float* __restrict__ ht,
    unsigned int* __restrict__ bar,
    const float* __restrict__ Uf, const float* __restrict__ Ub)
{
  int idx = blockIdx.x * 256 + threadIdx.x;
  // transpose U into ut[(d*512+u)*3 + g][k] = U_d[k][g*512+u]
  if (idx < 2*512*3*512) {
    int k = idx & 511;
    int r = idx >> 9;
    int g = r % 3;
    int rest = r / 3;        // d*512 + u
    int u = rest & 511;
    int dd = rest >> 9;
    const float* Um = dd ? Ub : Uf;
    ut[idx] = Um[k*GG + (g << 9) + u];
  }
  if (idx < 131072) ht[idx] = 0.0f;      // zero both h ping-pong buffers
  if (idx < 256) bar[idx] = 0u;          // zero arrival slots (every call: replays!)
  // mask -> float [t][b]; detect bool8 vs int32 storage via byte 1 (mask[0][1] true)
  if (idx < BB*TT) {
    int b = idx / TT, t = idx - b*TT;
    bool bytefmt = (mraw[1] == 1);
    bool mv = bytefmt ? (mraw[idx] != 0) : (((const int*)mraw)[idx] != 0);
    mf[t*BB + b] = mv ? 1.0f : 0.0f;
  }
}

// XG[t][g][u][b] = A(16000x1024) * W(1024x1536) + bias, both directions.
// m-tile = 64 b x 2 t (gathered rows) so the transposed epilogue writes
// b-contiguous float4s (full 64B lines within one wave) -> scan reads coalesced.
__global__ __launch_bounds__(256) void gemm_xg(
    const float* __restrict__ A,
    const float* __restrict__ Wf, const float* __restrict__ Wb,
    const float* __restrict__ bf, const float* __restrict__ bb,
    float* __restrict__ xgf, float* __restrict__ xgb)
{
  __shared__ float As[16][132];
  __shared__ float Bs[16][128];
  const int tid = threadIdx.x;
  const int t0 = blockIdx.x * 2;           // 125 t-pairs
  const int n0 = blockIdx.y * 128;         // 24 tiles over 3072
  const int d  = (n0 >= GG) ? 1 : 0;
  const int nl0 = n0 - d*GG;
  const float* Wm  = d ? Wb : Wf;
  const float* bias = d ? bb : bf;
  float* xg = d ? xgb : xgf;
  const int tm = (tid >> 4) << 3;
  const int tn = (tid & 15) << 2;          // cols {tn..tn+3, tn+64..tn+67}
  float acc[8][8];
  #pragma unroll
  for (int i = 0; i < 8; i++)
    #pragma unroll
    for (int j = 0; j < 8; j++) acc[i][j] = 0.0f;
  for (int k0 = 0; k0 < CC; k0 += 16) {
    #pragma unroll
    for (int j = 0; j < 2; j++) {
      int f = tid*2 + j;
      int r = f >> 2;                      // tile row 0..127 -> m=(r&63)*250+t0+(r>>6)
      int kk = (f & 3) << 2;
      int m = (r & 63)*TT + t0 + (r >> 6);
      float4 av = *(const float4*)(A + (size_t)m*CC + k0 + kk);
      As[kk+0][r] = av.x; As[kk+1][r] = av.y; As[kk+2][r] = av.z; As[kk+3][r] = av.w;
    }
    #pragma unroll
    for (int j = 0; j < 2; j++) {
      int f = tid*2 + j;
      int kr = f >> 5;
      int nn = (f & 31) << 2;
      *(float4*)&Bs[kr][nn] = *(const float4*)(Wm + (size_t)(k0+kr)*GG + nl0 + nn);
    }
    __syncthreads();
    #pragma unroll
    for (int k = 0; k < 16; k++) {
      float4 a0 = *(const float4*)&As[k][tm];
      float4 a1 = *(const float4*)&As[k][tm+4];
      float4 b0 = *(const float4*)&Bs[k][tn];
      float4 b1 = *(const float4*)&Bs[k][tn+64];
      float av[8] = {a0.x,a0.y,a0.z,a0.w,a1.x,a1.y,a1.z,a1.w};
      float bv[8] = {b0.x,b0.y,b0.z,b0.w,b1.x,b1.y,b1.z,b1.w};
      #pragma unroll
      for (int i = 0; i < 8; i++)
        #pragma unroll
        for (int jj = 0; jj < 8; jj++) acc[i][jj] = fmaf(av[i], bv[jj], acc[i][jj]);
    }
    __syncthreads();
  }
  // transposed epilogue: thread rows tm..tm+7 = 8 consecutive b at t = t0+(tm>>6)
  const int t  = t0 + (tm >> 6);
  const int b0 = tm & 63;
  float* xgt = xg + (size_t)t*98304 + b0;
  #pragma unroll
  for (int j = 0; j < 8; j++) {
    int n = nl0 + ((j < 4) ? (tn + j) : (tn + 60 + j));   // j>=4 -> tn+64+(j-4)
    int g = n >> 9, uu = n & 511;
    float bv = bias[n];
    float4 lo = {acc[0][j]+bv, acc[1][j]+bv, acc[2][j]+bv, acc[3][j]+bv};
    float4 hi = {acc[4][j]+bv, acc[5][j]+bv, acc[6][j]+bv, acc[7][j]+bv};
    float* o = xgt + ((size_t)g << 15) + (uu << 6);
    *(float4*)o = lo; *(float4*)(o+4) = hi;
  }
}

// Persistent scan, fence-free barrier (write-through h publish + L2-bypass
// staging). xg reads coalesced ([t][g][u][b]) and prefetched one step ahead.
__global__ __launch_bounds__(256, 1) void gru_scan(
    const float* __restrict__ xgf, const float* __restrict__ xgb,
    float* __restrict__ xgfw, float* __restrict__ xgbw,
    const float* __restrict__ ut, const float* __restrict__ bf,
    const float* __restrict__ bb, const float* __restrict__ mf,
    float* __restrict__ ht, unsigned int* __restrict__ bar,
    float* __restrict__ out)
{
  extern __shared__ float lds[];
  float* hbuf = lds;                 // 32768 floats: h[512 k][64 b]
  float* us   = lds + 32768;         // 6144 floats: U slice [4 wv][3 g][512 k]
  const int tid  = threadIdx.x;
  const int lane = tid & 63;               // batch b
  const int bid  = blockIdx.x;
  const int d    = bid >> 7;
  const int wv   = __builtin_amdgcn_readfirstlane(tid >> 6);
  const int u    = __builtin_amdgcn_readfirstlane(((bid & 127) << 2) | wv);
  // load U slice (block's 4 u rows = 6144 contiguous floats in ut)
  {
    const float4* usrc = (const float4*)(ut + (size_t)(((d << 9) + ((bid & 127) << 2)) * 3) * 512);
    float4* ud = (float4*)us;
    #pragma unroll
    for (int j = 0; j < 6; j++) ud[j*256 + tid] = usrc[j*256 + tid];
  }
  const float* uzL = us + (size_t)(wv*3) * 512;
  const float* urL = uzL + 512;
  const float* uhL = uzL + 1024;
  const float* bias = (d ? bb : bf) + GG;
  const float b1z = bias[u], b1r = bias[512+u], b1h = bias[1024+u];
  const float* xgr = d ? xgb : xgf;
  float* ywr = d ? xgbw : xgfw;
  float hprev = 0.0f, ysave = 0.0f;
  int tprev = 0;

  // prefetch step-0 xg (coalesced: 256 B/wave per gate) + mask
  const int tfirst = d ? (TT-1) : 0;
  const float* xp0 = xgr + (size_t)tfirst*98304 + (u << 6) + lane;
  float xz = xp0[0], xr = xp0[32768], xh = xp0[65536];
  float m = mf[tfirst*BB + lane];

  for (int s = 0; s < TT; s++) {
    const int t = d ? (TT-1-s) : s;
    if (s) {
      __syncthreads();   // step s-1 done; per-wave vmcnt drain before barrier
      if (tid == 0) {
        asm volatile("s_waitcnt vmcnt(0)" ::: "memory");
        __hip_atomic_store(&bar[bid], (unsigned)s, __ATOMIC_RELAXED, __HIP_MEMORY_SCOPE_AGENT);
      }
      if (tid < 64) {    // wave 0 polls own direction's 128 slots, dwordx2/lane
        const u64t* bp = (const u64t*)(bar + (d << 7));
        while (true) {
          u64t v = __hip_atomic_load(&bp[lane], __ATOMIC_RELAXED, __HIP_MEMORY_SCOPE_AGENT);
          if (__all(((unsigned)v >= (unsigned)s) && ((unsigned)(v >> 32) >= (unsigned)s))) break;
          __builtin_amdgcn_s_sleep(1);
        }
      }
      __syncthreads();
      // deferred y(t_prev) -> dead xg slot (g=0 region), coalesced [t][u][b]
      ywr[(size_t)tprev*98304 + ((size_t)u << 6) + lane] = ysave;
    }
    // stage h[512][64] via L2-bypass loads, 4 pipelined 32 KB chunks
    const float* hin = ht + (((s & 1) << 1 | d) << 15);
    {
      u64t st[16];
      u64t* sp = (u64t*)hin;
      #pragma unroll
      for (int j = 0; j < 16; j++)
        st[j] = __hip_atomic_load(&sp[j*256 + tid], __ATOMIC_RELAXED, __HIP_MEMORY_SCOPE_AGENT);
      u64t* dp = (u64t*)hbuf;
      #pragma unroll
      for (int j = 0; j < 16; j++) dp[j*256 + tid] = st[j];
    }
    __syncthreads();
    // prefetch NEXT step's xg + mask now; latency hides under 4-chunk compute
    float xz_n, xr_n, xh_n, m_n;
    if (s+1 < TT) {
      const int t2 = d ? (TT-2-s) : (s+1);
      const float* xp = xgr + (size_t)t2*98304 + (u << 6) + lane;
      xz_n = xp[0]; xr_n = xp[32768]; xh_n = xp[65536];
      m_n  = mf[t2*BB + lane];
    }
    float az0=0, az1=0, ar0=0, ar1=0, ah0=0, ah1=0;
    for (int c = 0; c < 4; c++) {
      u64t stg[16];
      if (c < 3) {       // issue next-chunk L2-bypass loads early
        u64t* sp = (u64t*)(hin + (c+1)*8192);
        #pragma unroll
        for (int j = 0; j < 16; j++)
          stg[j] = __hip_atomic_load(&sp[j*256 + tid], __ATOMIC_RELAXED, __HIP_MEMORY_SCOPE_AGENT);
      }
      const int k0 = c << 7;
      #pragma unroll 8
      for (int kq = 0; kq < 128; kq += 4) {
        const int k = k0 + kq;
        float4 z4 = *(const float4*)(uzL + k);   // uniform ds_read_b128 (broadcast)
        float4 r4 = *(const float4*)(urL + k);
        float4 h4 = *(const float4*)(uhL + k);
        float a0 = hbuf[((k+0) << 6) | lane];    // conflict-free (2 lanes/bank)
        float a1 = hbuf[((k+1) << 6) | lane];
        float a2 = hbuf[((k+2) << 6) | lane];
        float a3 = hbuf[((k+3) << 6) | lane];
        az0 = fmaf(a0, z4.x, az0); az1 = fmaf(a1, z4.y, az1);
        az0 = fmaf(a2, z4.z, az0); az1 = fmaf(a3, z4.w, az1);
        ar0 = fmaf(a0, r4.x, ar0); ar1 = fmaf(a1, r4.y, ar1);
        ar0 = fmaf(a2, r4.z, ar0); ar1 = fmaf(a3, r4.w, ar1);
        ah0 = fmaf(a0, h4.x, ah0); ah1 = fmaf(a1, h4.y, ah1);
        ah0 = fmaf(a2, h4.z, ah0); ah1 = fmaf(a3, h4.w, ah1);
      }
      if (c < 3) {       // write staged chunk, publish to all waves
        u64t* dp = (u64t*)(hbuf + (c+1)*8192);
        #pragma unroll
        for (int j = 0; j < 16; j++) dp[j*256 + tid] = stg[j];
        __syncthreads();
      }
    }
    float az = az0+az1, ar = ar0+ar1, ah = ah0+ah1;
    float z  = 1.0f / (1.0f + expf(-(xz + az + b1z)));
    float r  = 1.0f / (1.0f + expf(-(xr + ar + b1r)));
    float cc = tanhf(xh + r * (ah + b1h));
    float hn = z*hprev + (1.0f - z)*cc;
    hn = (m != 0.0f) ? hn : hprev;
    hprev = hn; ysave = hn; tprev = t;
    // publish h via write-through (no dirty L2 line): relaxed agent atomic
    float* hout = ht + ((((s & 1) ^ 1) << 1 | d) << 15);
    __hip_atomic_store(&hout[(u << 6) | lane], hn, __ATOMIC_RELAXED, __HIP_MEMORY_SCOPE_AGENT);
    if (s+1 < TT) { xz = xz_n; xr = xr_n; xh = xh_n; m = m_n; }
  }
  // final barrier orders last y overwrite vs other blocks' xg reads
  __syncthreads();
  if (tid == 0) {
    asm volatile("s_waitcnt vmcnt(0)" ::: "memory");
    __hip_atomic_store(&bar[bid], (unsigned)TT, __ATOMIC_RELAXED, __HIP_MEMORY_SCOPE_AGENT);
  }
  if (tid < 64) {
    const u64t* bp = (const u64t*)(bar + (d << 7));
    while (true) {
      u64t v = __hip_atomic_load(&bp[lane], __ATOMIC_RELAXED, __HIP_MEMORY_SCOPE_AGENT);
      if (__all(((unsigned)v >= (unsigned)TT) && ((unsigned)(v >> 32) >= (unsigned)TT))) break;
      __builtin_amdgcn_s_sleep(1);
    }
  }
  __syncthreads();
  ywr[(size_t)tprev*98304 + ((size_t)u << 6) + lane] = ysave;
  out[16384000ull + ((size_t)lane << 10) + (d << 9) + u] = hprev;  // state (once)
}

// out[b][t][d*512+u] <- y stored as [t][u][b] inside xg g=0 regions
__global__ __launch_bounds__(256) void y_transpose(
    const float* __restrict__ xgf, const float* __restrict__ xgb,
    float* __restrict__ out)
{
  __shared__ float tile[64][65];
  const int t  = blockIdx.x;
  const int ch = blockIdx.y;           // d*8 + uc
  const int d  = ch >> 3, uc = ch & 7;
  const float* src = (d ? xgb : xgf) + (size_t)t*98304 + (size_t)uc*4096;
  const int lane = threadIdx.x & 63, w = threadIdx.x >> 6;
  #pragma unroll
  for (int j = 0; j < 16; j++) {
    int r = j*4 + w;                   // u' within chunk
    tile[r][lane] = src[r*64 + lane];  // coalesced read (lane=b)
  }
  __syncthreads();
  #pragma unroll
  for (int j = 0; j < 16; j++) {
    int b = j*4 + w;
    out[((size_t)b*TT + t)*1024 + (d << 9) + (uc << 6) + lane] = tile[lane][b];
  }
}

extern "C" void kernel_launch(void* const* d_in, const int* in_sizes, int n_in,
                              void* d_out, int out_size, void* d_ws, size_t ws_size,
                              hipStream_t stream) {
  const float* X  = (const float*)d_in[0];
  const unsigned char* Mk = (const unsigned char*)d_in[1];
  const float* Wf = (const float*)d_in[2];
  const float* Uf = (const float*)d_in[3];
  const float* bf = (const float*)d_in[4];
  const float* Wb = (const float*)d_in[5];
  const float* Ub = (const float*)d_in[6];
  const float* bb = (const float*)d_in[7];
  float* out = (float*)d_out;
  float* ws  = (float*)d_ws;
  float* xgf = ws + O_XGF;
  float* xgb = ws + O_XGB;
  float* ut  = ws + O_UT;
  float* ht  = ws + O_HT;
  float* mf  = ws + O_MF;
  unsigned int* bar = (unsigned int*)(ws + O_BAR);

  hipFuncSetAttribute((const void*)gru_scan,
                      hipFuncAttributeMaxDynamicSharedMemorySize, 155648);

  prep_kernel<<<dim3(6144), dim3(256), 0, stream>>>(Mk, ut, mf, ht, bar, Uf, Ub);
  gemm_xg<<<dim3(125, 24), dim3(256), 0, stream>>>(X, Wf, Wb, bf, bb, xgf, xgb);
  gru_scan<<<dim3(NB), dim3(256), 155648, stream>>>(xgf, xgb, xgf, xgb, ut, bf, bb, mf, ht, bar, out);
  y_transpose<<<dim3(TT, 16), dim3(256), 0, stream>>>(xgf, xgb, out);
}

// Round 7
// 4981.989 us; speedup vs baseline: 2.0485x; 1.2324x over previous
//
#include <hip/hip_runtime.h>
#include <cmath>

#define BB 64
#define TT 250
#define CC 1024
#define UU 512
#define GG 1536   // 3U
#define NB 256    // scan grid: 1 block/CU (88 KB LDS), exactly co-resident

typedef unsigned long long u64t;

// workspace layout (float offsets)
#define O_XGF 0             // [t][g][u][b]; g=0 element (u,b) overwritten by y (same owner block)
#define O_XGB 24576000      // T*B*G = 250*64*1536
#define O_UT  49152000      // 2*512*3*512 = 1,572,864
#define O_MF  50724864      // T*B = 16,000
#define O_VH  50740864      // u64[2 buf][2 dir][512 u][64 b] = 131,072 u64 = 262,144 floats
// total 51,003,008 floats ≈ 194.6 MiB

__global__ __launch_bounds__(256) void prep_kernel(
    const unsigned char* __restrict__ mraw,
    float* __restrict__ ut, float* __restrict__ mf, u64t* __restrict__ vh,
    const float* __restrict__ Uf, const float* __restrict__ Ub)
{
  int idx = blockIdx.x * 256 + threadIdx.x;
  // transpose U into ut[(d*512+u)*3 + g][k] = U_d[k][g*512+u]
  if (idx < 2*512*3*512) {
    int k = idx & 511;
    int r = idx >> 9;
    int g = r % 3;
    int rest = r / 3;        // d*512 + u
    int u = rest & 511;
    int dd = rest >> 9;
    const float* Um = dd ? Ub : Uf;
    ut[idx] = Um[k*GG + (g << 9) + u];
  }
  // init versioned h: {h=0.0f, tag=0} both ping-pong buffers, via the SAME
  // sc0sc1 write-through path the scan reads with (L2-bypass coherence).
  if (idx < 131072)
    __hip_atomic_store(&vh[idx], 0ULL, __ATOMIC_RELAXED, __HIP_MEMORY_SCOPE_AGENT);
  // mask -> float [t][b]; detect bool8 vs int32 storage via byte 1 (mask[0][1] true)
  if (idx < BB*TT) {
    int b = idx / TT, t = idx - b*TT;
    bool bytefmt = (mraw[1] == 1);
    bool mv = bytefmt ? (mraw[idx] != 0) : (((const int*)mraw)[idx] != 0);
    mf[t*BB + b] = mv ? 1.0f : 0.0f;
  }
}

// XG[t][g][u][b] = A(16000x1024) * W(1024x1536) + bias, both directions.
// m-tile = 64 b x 2 t (gathered rows); transposed epilogue writes b-contiguous
// float4s (full 64B lines within one wave) -> scan reads coalesced.
__global__ __launch_bounds__(256) void gemm_xg(
    const float* __restrict__ A,
    const float* __restrict__ Wf, const float* __restrict__ Wb,
    const float* __restrict__ bf, const float* __restrict__ bb,
    float* __restrict__ xgf, float* __restrict__ xgb)
{
  __shared__ float As[16][132];
  __shared__ float Bs[16][128];
  const int tid = threadIdx.x;
  const int t0 = blockIdx.x * 2;           // 125 t-pairs
  const int n0 = blockIdx.y * 128;         // 24 tiles over 3072
  const int d  = (n0 >= GG) ? 1 : 0;
  const int nl0 = n0 - d*GG;
  const float* Wm  = d ? Wb : Wf;
  const float* bias = d ? bb : bf;
  float* xg = d ? xgb : xgf;
  const int tm = (tid >> 4) << 3;
  const int tn = (tid & 15) << 2;          // cols {tn..tn+3, tn+64..tn+67}
  float acc[8][8];
  #pragma unroll
  for (int i = 0; i < 8; i++)
    #pragma unroll
    for (int j = 0; j < 8; j++) acc[i][j] = 0.0f;
  for (int k0 = 0; k0 < CC; k0 += 16) {
    #pragma unroll
    for (int j = 0; j < 2; j++) {
      int f = tid*2 + j;
      int r = f >> 2;                      // tile row 0..127 -> m=(r&63)*250+t0+(r>>6)
      int kk = (f & 3) << 2;
      int m = (r & 63)*TT + t0 + (r >> 6);
      float4 av = *(const float4*)(A + (size_t)m*CC + k0 + kk);
      As[kk+0][r] = av.x; As[kk+1][r] = av.y; As[kk+2][r] = av.z; As[kk+3][r] = av.w;
    }
    #pragma unroll
    for (int j = 0; j < 2; j++) {
      int f = tid*2 + j;
      int kr = f >> 5;
      int nn = (f & 31) << 2;
      *(float4*)&Bs[kr][nn] = *(const float4*)(Wm + (size_t)(k0+kr)*GG + nl0 + nn);
    }
    __syncthreads();
    #pragma unroll
    for (int k = 0; k < 16; k++) {
      float4 a0 = *(const float4*)&As[k][tm];
      float4 a1 = *(const float4*)&As[k][tm+4];
      float4 b0 = *(const float4*)&Bs[k][tn];
      float4 b1 = *(const float4*)&Bs[k][tn+64];
      float av[8] = {a0.x,a0.y,a0.z,a0.w,a1.x,a1.y,a1.z,a1.w};
      float bv[8] = {b0.x,b0.y,b0.z,b0.w,b1.x,b1.y,b1.z,b1.w};
      #pragma unroll
      for (int i = 0; i < 8; i++)
        #pragma unroll
        for (int jj = 0; jj < 8; jj++) acc[i][jj] = fmaf(av[i], bv[jj], acc[i][jj]);
    }
    __syncthreads();
  }
  const int t  = t0 + (tm >> 6);
  const int b0 = tm & 63;
  float* xgt = xg + (size_t)t*98304 + b0;
  #pragma unroll
  for (int j = 0; j < 8; j++) {
    int n = nl0 + ((j < 4) ? (tn + j) : (tn + 60 + j));   // j>=4 -> tn+64+(j-4)
    int g = n >> 9, uu = n & 511;
    float bv = bias[n];
    float4 lo = {acc[0][j]+bv, acc[1][j]+bv, acc[2][j]+bv, acc[3][j]+bv};
    float4 hi = {acc[4][j]+bv, acc[5][j]+bv, acc[6][j]+bv, acc[7][j]+bv};
    float* o = xgt + ((size_t)g << 15) + (uu << 6);
    *(float4*)o = lo; *(float4*)(o+4) = hi;
  }
}

// --- versioned-payload staging helpers (32 u64 per thread per 32KB chunk) ---
#define ISSUE(vv, base_) do { \
    _Pragma("unroll") \
    for (int jj = 0; jj < 16; jj++) { \
      u64t* pp = (u64t*)(base_) + jj*512 + (tid << 1); \
      vv[2*jj]   = __hip_atomic_load(pp,   __ATOMIC_RELAXED, __HIP_MEMORY_SCOPE_AGENT); \
      vv[2*jj+1] = __hip_atomic_load(pp+1, __ATOMIC_RELAXED, __HIP_MEMORY_SCOPE_AGENT); \
    } } while (0)

#define CLEAN(vv, base_) do { \
    while (true) { \
      int bad_ = 0; \
      _Pragma("unroll") \
      for (int jj = 0; jj < 32; jj++) bad_ |= ((unsigned)(vv[jj] >> 32) < us_) ? 1 : 0; \
      if (!__any(bad_)) break; \
      __builtin_amdgcn_s_sleep(1); \
      _Pragma("unroll") \
      for (int jj = 0; jj < 16; jj++) { \
        u64t* pp = (u64t*)(base_) + jj*512 + (tid << 1); \
        if ((unsigned)(vv[2*jj]   >> 32) < us_) vv[2*jj]   = __hip_atomic_load(pp,   __ATOMIC_RELAXED, __HIP_MEMORY_SCOPE_AGENT); \
        if ((unsigned)(vv[2*jj+1] >> 32) < us_) vv[2*jj+1] = __hip_atomic_load(pp+1, __ATOMIC_RELAXED, __HIP_MEMORY_SCOPE_AGENT); \
      } \
    } } while (0)

#define WLDS(vv, dst2_) do { \
    _Pragma("unroll") \
    for (int jj = 0; jj < 16; jj++) { \
      float2 f2_; \
      f2_.x = __uint_as_float((unsigned)vv[2*jj]); \
      f2_.y = __uint_as_float((unsigned)vv[2*jj+1]); \
      (dst2_)[jj*256 + tid] = f2_; \
    } } while (0)

// Persistent scan, NO barrier: h published as atomic u64 {f32 h, u32 tag}
// (write-through to L3); consumers stage by loading versioned words and
// re-polling only stale elements. One L3 round-trip of sync per step.
__global__ __launch_bounds__(256, 1) void gru_scan(
    float* xgf, float* xgb,                 // read xg, write y in place (own (u,b) only)
    const float* __restrict__ ut, const float* __restrict__ bf,
    const float* __restrict__ bb, const float* __restrict__ mf,
    u64t* vh, float* __restrict__ out)
{
  extern __shared__ float lds[];
  float* hb0 = lds;                  // 8192 floats: chunk buffer A [128 k][64 b]
  float* hb1 = lds + 8192;           // 8192 floats: chunk buffer B
  float* us  = lds + 16384;          // 6144 floats: U slice [4 wv][3 g][512 k]
  const int tid  = threadIdx.x;
  const int lane = tid & 63;               // batch b
  const int bid  = blockIdx.x;
  const int d    = bid >> 7;
  const int wv   = __builtin_amdgcn_readfirstlane(tid >> 6);
  const int u    = __builtin_amdgcn_readfirstlane(((bid & 127) << 2) | wv);
  // load U slice (block's 4 u rows = 6144 contiguous floats in ut)
  {
    const float4* usrc = (const float4*)(ut + (size_t)(((d << 9) + ((bid & 127) << 2)) * 3) * 512);
    float4* ud = (float4*)us;
    #pragma unroll
    for (int j = 0; j < 6; j++) ud[j*256 + tid] = usrc[j*256 + tid];
  }
  const float* uzL = us + (size_t)(wv*3) * 512;
  const float* urL = uzL + 512;
  const float* uhL = uzL + 1024;
  const float* bias = (d ? bb : bf) + GG;
  const float b1z = bias[u], b1r = bias[512+u], b1h = bias[1024+u];
  float* xg = d ? xgb : xgf;
  float hprev = 0.0f;

  // prefetch step-0 xg (coalesced 256 B/wave per gate) + mask
  {
  }
  const int tfirst = d ? (TT-1) : 0;
  const float* xp0 = xg + (size_t)tfirst*98304 + (u << 6) + lane;
  float xz = xp0[0], xr = xp0[32768], xh = xp0[65536];
  float m = mf[tfirst*BB + lane];

  for (int s = 0; s < TT; s++) {
    const unsigned us_ = (unsigned)s;
    const int t = d ? (TT-1-s) : s;
    u64t* vin = vh + (size_t)((((unsigned)s & 1u) << 1) | (unsigned)d) * 32768;
    // ---- chunk 0: versioned stage (this IS the barrier) ----
    u64t v[32];
    ISSUE(v, vin);
    CLEAN(v, vin);
    WLDS(v, ((float2*)hb0));
    __syncthreads();
    // prefetch NEXT step's xg + mask; latency hides under 4-chunk compute
    float xz_n = 0.f, xr_n = 0.f, xh_n = 0.f, m_n = 0.f;
    if (s+1 < TT) {
      const int t2 = d ? (TT-2-s) : (s+1);
      const float* xp = xg + (size_t)t2*98304 + (u << 6) + lane;
      xz_n = xp[0]; xr_n = xp[32768]; xh_n = xp[65536];
      m_n  = mf[t2*BB + lane];
    }
    float az0=0, az1=0, ar0=0, ar1=0, ah0=0, ah1=0;
    for (int c = 0; c < 4; c++) {
      u64t w[32];
      if (c < 3) ISSUE(w, vin + (c+1)*8192);   // issue early, hide under compute
      const float* cur = (c & 1) ? hb1 : hb0;
      const int kb = c << 7;
      #pragma unroll 8
      for (int kq = 0; kq < 128; kq += 4) {
        const int k = kb + kq;
        float4 z4 = *(const float4*)(uzL + k);   // uniform ds_read_b128 (broadcast)
        float4 r4 = *(const float4*)(urL + k);
        float4 h4 = *(const float4*)(uhL + k);
        float a0 = cur[((kq+0) << 6) | lane];    // conflict-free (2 lanes/bank)
        float a1 = cur[((kq+1) << 6) | lane];
        float a2 = cur[((kq+2) << 6) | lane];
        float a3 = cur[((kq+3) << 6) | lane];
        az0 = fmaf(a0, z4.x, az0); az1 = fmaf(a1, z4.y, az1);
        az0 = fmaf(a2, z4.z, az0); az1 = fmaf(a3, z4.w, az1);
        ar0 = fmaf(a0, r4.x, ar0); ar1 = fmaf(a1, r4.y, ar1);
        ar0 = fmaf(a2, r4.z, ar0); ar1 = fmaf(a3, r4.w, ar1);
        ah0 = fmaf(a0, h4.x, ah0); ah1 = fmaf(a1, h4.y, ah1);
        ah0 = fmaf(a2, h4.z, ah0); ah1 = fmaf(a3, h4.w, ah1);
      }
      if (c < 3) {
        CLEAN(w, vin + (c+1)*8192);
        WLDS(w, ((float2*)((c & 1) ? hb0 : hb1)));
        __syncthreads();
      }
    }
    float az = az0+az1, ar = ar0+ar1, ah = ah0+ah1;
    float z  = 1.0f / (1.0f + expf(-(xz + az + b1z)));
    float r  = 1.0f / (1.0f + expf(-(xr + ar + b1r)));
    float cc = tanhf(xh + r * (ah + b1h));
    float hn = z*hprev + (1.0f - z)*cc;
    hn = (m != 0.0f) ? hn : hprev;
    hprev = hn;
    // publish versioned h_{s+1}: single atomic u64 {h, tag=s+1}, write-through
    u64t* vout = vh + (size_t)(((((unsigned)s+1u) & 1u) << 1) | (unsigned)d) * 32768;
    u64t pk = ((u64t)(unsigned)(s+1) << 32) | (u64t)__float_as_uint(hn);
    __hip_atomic_store(&vout[(u << 6) | lane], pk, __ATOMIC_RELAXED, __HIP_MEMORY_SCOPE_AGENT);
    // y(t) -> own g=0 xg element (read this step, never touched by other blocks)
    xg[(size_t)t*98304 + ((size_t)u << 6) + lane] = hn;
    if (s+1 < TT) { xz = xz_n; xr = xr_n; xh = xh_n; m = m_n; }
  }
  out[16384000ull + ((size_t)lane << 10) + (d << 9) + u] = hprev;  // state (once)
}

// out[b][t][d*512+u] <- y stored as [t][u][b] inside xg g=0 regions
__global__ __launch_bounds__(256) void y_transpose(
    const float* __restrict__ xgf, const float* __restrict__ xgb,
    float* __restrict__ out)
{
  __shared__ float tile[64][65];
  const int t  = blockIdx.x;
  const int ch = blockIdx.y;           // d*8 + uc
  const int d  = ch >> 3, uc = ch & 7;
  const float* src = (d ? xgb : xgf) + (size_t)t*98304 + (size_t)uc*4096;
  const int lane = threadIdx.x & 63, w = threadIdx.x >> 6;
  #pragma unroll
  for (int j = 0; j < 16; j++) {
    int r = j*4 + w;                   // u' within chunk
    tile[r][lane] = src[r*64 + lane];  // coalesced read (lane=b)
  }
  __syncthreads();
  #pragma unroll
  for (int j = 0; j < 16; j++) {
    int b = j*4 + w;
    out[((size_t)b*TT + t)*1024 + (d << 9) + (uc << 6) + lane] = tile[lane][b];
  }
}

extern "C" void kernel_launch(void* const* d_in, const int* in_sizes, int n_in,
                              void* d_out, int out_size, void* d_ws, size_t ws_size,
                              hipStream_t stream) {
  const float* X  = (const float*)d_in[0];
  const unsigned char* Mk = (const unsigned char*)d_in[1];
  const float* Wf = (const float*)d_in[2];
  const float* Uf = (const float*)d_in[3];
  const float* bf = (const float*)d_in[4];
  const float* Wb = (const float*)d_in[5];
  const float* Ub = (const float*)d_in[6];
  const float* bb = (const float*)d_in[7];
  float* out = (float*)d_out;
  float* ws  = (float*)d_ws;
  float* xgf = ws + O_XGF;
  float* xgb = ws + O_XGB;
  float* ut  = ws + O_UT;
  float* mf  = ws + O_MF;
  u64t*  vh  = (u64t*)(ws + O_VH);

  hipFuncSetAttribute((const void*)gru_scan,
                      hipFuncAttributeMaxDynamicSharedMemorySize, 90112);

  prep_kernel<<<dim3(6144), dim3(256), 0, stream>>>(Mk, ut, mf, vh, Uf, Ub);
  gemm_xg<<<dim3(125, 24), dim3(256), 0, stream>>>(X, Wf, Wb, bf, bb, xgf, xgb);
  gru_scan<<<dim3(NB), dim3(256), 90112, stream>>>(xgf, xgb, ut, bf, bb, mf, vh, out);
  y_transpose<<<dim3(TT, 16), dim3(256), 0, stream>>>(xgf, xgb, out);
}

// Round 8
// 2545.604 us; speedup vs baseline: 4.0090x; 1.9571x over previous
//
#include <hip/hip_runtime.h>
#include <cmath>

#define BB 64
#define TT 250
#define CC 1024
#define GG 1536   // 3U
#define NB 256    // scan grid: 1 block/CU, exactly co-resident

typedef unsigned long long u64t;
typedef __attribute__((ext_vector_type(8))) short short8v;
typedef __attribute__((ext_vector_type(4))) float f32x4;

// workspace layout (float offsets) — identical to R7
#define O_XGF 0             // [t][g][u][b]; g=0 element (u,b) overwritten by y (same owner thread)
#define O_XGB 24576000      // T*B*G
#define O_UT  49152000      // 2*512*3*512
#define O_MF  50724864      // T*B
#define O_VH  50740864      // u64[2 buf][2 dir][512 u][64 b]

__device__ __forceinline__ unsigned short f2bf(float f) {
  unsigned u = __float_as_uint(f);
  return (unsigned short)((u + 0x7fffu + ((u >> 16) & 1u)) >> 16);   // RNE
}
__device__ __forceinline__ float bf2f(unsigned short h) {
  return __uint_as_float((unsigned)h << 16);
}

__global__ __launch_bounds__(256) void prep_kernel(
    const unsigned char* __restrict__ mraw,
    float* __restrict__ ut, float* __restrict__ mf, u64t* __restrict__ vh,
    const float* __restrict__ Uf, const float* __restrict__ Ub)
{
  int idx = blockIdx.x * 256 + threadIdx.x;
  // transpose U into ut[(d*512+u)*3 + g][k] = U_d[k][g*512+u]
  if (idx < 2*512*3*512) {
    int k = idx & 511;
    int r = idx >> 9;
    int g = r % 3;
    int rest = r / 3;
    int u = rest & 511;
    int dd = rest >> 9;
    const float* Um = dd ? Ub : Uf;
    ut[idx] = Um[k*GG + (g << 9) + u];
  }
  // init versioned h {h=0, tag=0}, both ping-pong buffers (every call: replays!)
  if (idx < 131072)
    __hip_atomic_store(&vh[idx], 0ULL, __ATOMIC_RELAXED, __HIP_MEMORY_SCOPE_AGENT);
  // mask -> float [t][b]; detect bool8 vs int32 storage via byte 1 (mask[0][1] true)
  if (idx < BB*TT) {
    int b = idx / TT, t = idx - b*TT;
    bool bytefmt = (mraw[1] == 1);
    bool mv = bytefmt ? (mraw[idx] != 0) : (((const int*)mraw)[idx] != 0);
    mf[t*BB + b] = mv ? 1.0f : 0.0f;
  }
}

// XG[t][g][u][b] = A(16000x1024) * W(1024x1536) + bias, both directions.
__global__ __launch_bounds__(256) void gemm_xg(
    const float* __restrict__ A,
    const float* __restrict__ Wf, const float* __restrict__ Wb,
    const float* __restrict__ bf, const float* __restrict__ bb,
    float* __restrict__ xgf, float* __restrict__ xgb)
{
  __shared__ float As[16][132];
  __shared__ float Bs[16][128];
  const int tid = threadIdx.x;
  const int t0 = blockIdx.x * 2;
  const int n0 = blockIdx.y * 128;
  const int d  = (n0 >= GG) ? 1 : 0;
  const int nl0 = n0 - d*GG;
  const float* Wm  = d ? Wb : Wf;
  const float* bias = d ? bb : bf;
  float* xg = d ? xgb : xgf;
  const int tm = (tid >> 4) << 3;
  const int tn = (tid & 15) << 2;
  float acc[8][8];
  #pragma unroll
  for (int i = 0; i < 8; i++)
    #pragma unroll
    for (int j = 0; j < 8; j++) acc[i][j] = 0.0f;
  for (int k0 = 0; k0 < CC; k0 += 16) {
    #pragma unroll
    for (int j = 0; j < 2; j++) {
      int f = tid*2 + j;
      int r = f >> 2;
      int kk = (f & 3) << 2;
      int m = (r & 63)*TT + t0 + (r >> 6);
      float4 av = *(const float4*)(A + (size_t)m*CC + k0 + kk);
      As[kk+0][r] = av.x; As[kk+1][r] = av.y; As[kk+2][r] = av.z; As[kk+3][r] = av.w;
    }
    #pragma unroll
    for (int j = 0; j < 2; j++) {
      int f = tid*2 + j;
      int kr = f >> 5;
      int nn = (f & 31) << 2;
      *(float4*)&Bs[kr][nn] = *(const float4*)(Wm + (size_t)(k0+kr)*GG + nl0 + nn);
    }
    __syncthreads();
    #pragma unroll
    for (int k = 0; k < 16; k++) {
      float4 a0 = *(const float4*)&As[k][tm];
      float4 a1 = *(const float4*)&As[k][tm+4];
      float4 b0 = *(const float4*)&Bs[k][tn];
      float4 b1 = *(const float4*)&Bs[k][tn+64];
      float av[8] = {a0.x,a0.y,a0.z,a0.w,a1.x,a1.y,a1.z,a1.w};
      float bv[8] = {b0.x,b0.y,b0.z,b0.w,b1.x,b1.y,b1.z,b1.w};
      #pragma unroll
      for (int i = 0; i < 8; i++)
        #pragma unroll
        for (int jj = 0; jj < 8; jj++) acc[i][jj] = fmaf(av[i], bv[jj], acc[i][jj]);
    }
    __syncthreads();
  }
  const int t  = t0 + (tm >> 6);
  const int b0 = tm & 63;
  float* xgt = xg + (size_t)t*98304 + b0;
  #pragma unroll
  for (int j = 0; j < 8; j++) {
    int n = nl0 + ((j < 4) ? (tn + j) : (tn + 60 + j));
    int g = n >> 9, uu = n & 511;
    float bv = bias[n];
    float4 lo = {acc[0][j]+bv, acc[1][j]+bv, acc[2][j]+bv, acc[3][j]+bv};
    float4 hi = {acc[4][j]+bv, acc[5][j]+bv, acc[6][j]+bv, acc[7][j]+bv};
    float* o = xgt + ((size_t)g << 15) + (uu << 6);
    *(float4*)o = lo; *(float4*)(o+4) = hi;
  }
}

// Persistent scan via bf16x3 MFMA. Block = (d, 16 u, 16 b); per dir the A-matrix
// is U'' with 4-row groups (z,r,h,pad) per u -> M=2048, N=64, K=512.
// A-fragments (constant) live in VGPRs; only H is staged per step (bf16 hi/lo
// B-frag layout in LDS). Sync = R7's u64 {h,tag} versioned payload.
__global__ __launch_bounds__(256, 1) void gru_scan(
    float* xgf, float* xgb,
    const float* __restrict__ ut, const float* __restrict__ bf,
    const float* __restrict__ bb, const float* __restrict__ mf,
    u64t* vh, float* __restrict__ out)
{
  __shared__ __align__(16) unsigned short Bhi[8192];  // [ksub16][b16][kw32] 16 KB
  __shared__ __align__(16) unsigned short Blo[8192];
  const int tid = threadIdx.x;
  const int l   = tid & 63;
  const int wv  = tid >> 6;
  const int bid = blockIdx.x;
  const int d     = bid >> 7;
  const int mb    = (bid >> 2) & 31;     // 32 m-blocks/dir (16 u each)
  const int btile = bid & 3;             // 4 b-tiles (16 b each)

  // ---- A-fragments: wave's 16-row m-tile (rows = 4 per u: z,r,h,pad), VGPR-resident ----
  short8v af_hi[16], af_lo[16];
  {
    const int row = (wv << 4) | (l & 15);        // row in block's 64-row m-block
    const int g   = row & 3;
    const int ua  = (mb << 4) | (row >> 2);      // u owning this row
    const int kg  = (l >> 4) << 3;               // k-offset within ksub: lane-group*8
    if (g < 3) {
      const float* ap = ut + (((size_t)(((d << 9) | ua) * 3 + g)) << 9);
      #pragma unroll
      for (int ks = 0; ks < 16; ks++) {
        #pragma unroll
        for (int j = 0; j < 8; j++) {
          float f = ap[(ks << 5) + kg + j];
          unsigned short h = f2bf(f);
          af_hi[ks][j] = (short)h;
          af_lo[ks][j] = (short)f2bf(f - bf2f(h));
        }
      }
    } else {           // pad row: zeros
      #pragma unroll
      for (int ks = 0; ks < 16; ks++)
        #pragma unroll
        for (int j = 0; j < 8; j++) { af_hi[ks][j] = 0; af_lo[ks][j] = 0; }
    }
  }

  // output role: C-frag col = lane&15 -> b; rows (lane>>4)*4+reg -> u, gate=reg
  const int a  = l >> 4;
  const int u  = (mb << 4) | (wv << 2) | a;
  const int b  = (btile << 4) | (l & 15);
  const float* bias = (d ? bb : bf) + GG;
  const float b1z = bias[u], b1r = bias[512+u], b1h = bias[1024+u];
  float* xg = d ? xgb : xgf;
  float hprev = 0.0f;

  // staging role: thread (kc = tid>>4, bl = tid&15) owns k = kc*32..+31 at col b
  const int kc = tid >> 4;
  const int blw = tid & 15;
  const int cb = (btile << 4) | blw;
  // B-frag read byte offset within a ksub plane (swizzled quads)
  const int boff = ((l & 15) << 6) + (((l >> 4) ^ ((l >> 1) & 3)) << 4);

  // step-0 xg + mask prefetch
  const int tf = d ? (TT-1) : 0;
  const float* xp0 = xg + (size_t)tf*98304 + (u << 6) + b;
  float xz = xp0[0], xr = xp0[32768], xh = xp0[65536];
  float m = mf[tf*BB + b];

  for (int s = 0; s < TT; s++) {
    const unsigned us_ = (unsigned)s;
    const int t = d ? (TT-1-s) : s;
    u64t* vin = vh + (size_t)((((unsigned)s & 1u) << 1) | (unsigned)d) * 32768;

    // ---- versioned stage of H columns (this IS the barrier) ----
    u64t v[32];
    #pragma unroll
    for (int i = 0; i < 32; i++)
      v[i] = __hip_atomic_load(vin + ((kc << 5) + i)*64 + cb, __ATOMIC_RELAXED, __HIP_MEMORY_SCOPE_AGENT);
    while (true) {
      int bad = 0;
      #pragma unroll
      for (int i = 0; i < 32; i++) bad |= ((unsigned)(v[i] >> 32) < us_) ? 1 : 0;
      if (!__any(bad)) break;
      __builtin_amdgcn_s_sleep(1);
      #pragma unroll
      for (int i = 0; i < 32; i++)
        if ((unsigned)(v[i] >> 32) < us_)
          v[i] = __hip_atomic_load(vin + ((kc << 5) + i)*64 + cb, __ATOMIC_RELAXED, __HIP_MEMORY_SCOPE_AGENT);
    }

    __syncthreads();     // all waves done reading previous step's B-frags
    // cvt f32 -> bf16 hi/lo, pack, write swizzled B-frag rows (4+4 b128/thread)
    #pragma unroll
    for (int q = 0; q < 4; q++) {
      unsigned hv[4], lv[4];
      #pragma unroll
      for (int p = 0; p < 4; p++) {
        float f0 = __uint_as_float((unsigned)v[(q << 3) + (p << 1)]);
        float f1 = __uint_as_float((unsigned)v[(q << 3) + (p << 1) + 1]);
        unsigned short h0 = f2bf(f0), h1 = f2bf(f1);
        hv[p] = (unsigned)h0 | ((unsigned)h1 << 16);
        lv[p] = (unsigned)f2bf(f0 - bf2f(h0)) | ((unsigned)f2bf(f1 - bf2f(h1)) << 16);
      }
      const int phys = q ^ ((blw >> 1) & 3);
      const int off = (kc << 10) + (blw << 6) + (phys << 4);
      *(uint4*)((char*)Bhi + off) = make_uint4(hv[0], hv[1], hv[2], hv[3]);
      *(uint4*)((char*)Blo + off) = make_uint4(lv[0], lv[1], lv[2], lv[3]);
    }
    __syncthreads();     // B ready for all waves

    // prefetch next step's xg/mask; latency hides under MFMA
    float xz_n = 0.f, xr_n = 0.f, xh_n = 0.f, m_n = 0.f;
    if (s+1 < TT) {
      const int t2 = d ? (TT-2-s) : (s+1);
      const float* xp = xg + (size_t)t2*98304 + (u << 6) + b;
      xz_n = xp[0]; xr_n = xp[32768]; xh_n = xp[65536];
      m_n  = mf[t2*BB + b];
    }

    // ---- bf16x3 MFMA: 16 ksub x {hi*hi, hi*lo, lo*hi} ----
    f32x4 acc0 = {0.f,0.f,0.f,0.f};
    f32x4 acc1 = {0.f,0.f,0.f,0.f};
    f32x4 acc2 = {0.f,0.f,0.f,0.f};
    #pragma unroll
    for (int ks = 0; ks < 16; ks++) {
      short8v bh  = *(const short8v*)((const char*)Bhi + (ks << 10) + boff);
      short8v bl8 = *(const short8v*)((const char*)Blo + (ks << 10) + boff);
      acc0 = __builtin_amdgcn_mfma_f32_16x16x32_bf16(af_hi[ks], bh,  acc0, 0, 0, 0);
      acc1 = __builtin_amdgcn_mfma_f32_16x16x32_bf16(af_hi[ks], bl8, acc1, 0, 0, 0);
      acc2 = __builtin_amdgcn_mfma_f32_16x16x32_bf16(af_lo[ks], bh,  acc2, 0, 0, 0);
    }
    float az = acc0[0] + acc1[0] + acc2[0];   // reg0 = z-row of this u
    float ar = acc0[1] + acc1[1] + acc2[1];   // reg1 = r-row
    float ah = acc0[2] + acc1[2] + acc2[2];   // reg2 = h-row (reg3 = pad)

    float z  = 1.0f / (1.0f + expf(-(xz + az + b1z)));
    float r  = 1.0f / (1.0f + expf(-(xr + ar + b1r)));
    float cc = tanhf(xh + r * (ah + b1h));
    float hn = z*hprev + (1.0f - z)*cc;
    hn = (m != 0.0f) ? hn : hprev;
    hprev = hn;

    // publish versioned h_{s+1}; write y(t) into own dead g=0 xg slot
    u64t* vout = vh + (size_t)(((((unsigned)s + 1u) & 1u) << 1) | (unsigned)d) * 32768;
    u64t pk = ((u64t)(unsigned)(s+1) << 32) | (u64t)__float_as_uint(hn);
    __hip_atomic_store(&vout[(u << 6) | b], pk, __ATOMIC_RELAXED, __HIP_MEMORY_SCOPE_AGENT);
    xg[(size_t)t*98304 + ((size_t)u << 6) + b] = hn;
    xz = xz_n; xr = xr_n; xh = xh_n; m = m_n;
  }
  out[16384000ull + ((size_t)b << 10) + (d << 9) + u] = hprev;  // state (once)
}

// out[b][t][d*512+u] <- y stored as [t][u][b] inside xg g=0 regions
__global__ __launch_bounds__(256) void y_transpose(
    const float* __restrict__ xgf, const float* __restrict__ xgb,
    float* __restrict__ out)
{
  __shared__ float tile[64][65];
  const int t  = blockIdx.x;
  const int ch = blockIdx.y;
  const int d  = ch >> 3, uc = ch & 7;
  const float* src = (d ? xgb : xgf) + (size_t)t*98304 + (size_t)uc*4096;
  const int lane = threadIdx.x & 63, w = threadIdx.x >> 6;
  #pragma unroll
  for (int j = 0; j < 16; j++) {
    int r = j*4 + w;
    tile[r][lane] = src[r*64 + lane];
  }
  __syncthreads();
  #pragma unroll
  for (int j = 0; j < 16; j++) {
    int b = j*4 + w;
    out[((size_t)b*TT + t)*1024 + (d << 9) + (uc << 6) + lane] = tile[lane][b];
  }
}

extern "C" void kernel_launch(void* const* d_in, const int* in_sizes, int n_in,
                              void* d_out, int out_size, void* d_ws, size_t ws_size,
                              hipStream_t stream) {
  const float* X  = (const float*)d_in[0];
  const unsigned char* Mk = (const unsigned char*)d_in[1];
  const float* Wf = (const float*)d_in[2];
  const float* Uf = (const float*)d_in[3];
  const float* bf = (const float*)d_in[4];
  const float* Wb = (const float*)d_in[5];
  const float* Ub = (const float*)d_in[6];
  const float* bb = (const float*)d_in[7];
  float* out = (float*)d_out;
  float* ws  = (float*)d_ws;
  float* xgf = ws + O_XGF;
  float* xgb = ws + O_XGB;
  float* ut  = ws + O_UT;
  float* mf  = ws + O_MF;
  u64t*  vh  = (u64t*)(ws + O_VH);

  prep_kernel<<<dim3(6144), dim3(256), 0, stream>>>(Mk, ut, mf, vh, Uf, Ub);
  gemm_xg<<<dim3(125, 24), dim3(256), 0, stream>>>(X, Wf, Wb, bf, bb, xgf, xgb);
  gru_scan<<<dim3(NB), dim3(256), 0, stream>>>(xgf, xgb, ut, bf, bb, mf, vh, out);
  y_transpose<<<dim3(TT, 16), dim3(256), 0, stream>>>(xgf, xgb, out);
}

// Round 10
// 1767.113 us; speedup vs baseline: 5.7752x; 1.4405x over previous
//
#include <hip/hip_runtime.h>
#include <cmath>

#define BB 64
#define TT 250
#define CC 1024
#define GG 1536   // 3U
#define NB 256    // scan grid: 1 block/CU, exactly co-resident

typedef unsigned long long u64t;
typedef unsigned int uint32;
typedef unsigned short ushort16;
typedef __attribute__((ext_vector_type(8))) short short8v;
typedef __attribute__((ext_vector_type(4))) float f32x4;

// workspace layout (float offsets)
#define O_XGF 0             // [t][g][u][b]; g=0 element (u,b) overwritten by y (same owner thread)
#define O_XGB 24576000      // T*B*G
#define O_UT  49152000      // 2*512*3*512
#define O_MF  50724864      // T*B
#define O_VH  50740864      // u64[2 buf][2 dir][512 u][64 b] = 262,144 float-slots
#define O_WT  51003008      // bf16 Wt: hi[2][1536][1024] + lo[2][1536][1024] = 3,145,728 float-slots
// total 54,148,736 floats ≈ 216.6 MiB

__device__ __forceinline__ unsigned short f2bf(float f) {
  unsigned u = __float_as_uint(f);
  return (unsigned short)((u + 0x7fffu + ((u >> 16) & 1u)) >> 16);   // RNE
}
__device__ __forceinline__ float bf2f(unsigned short h) {
  return __uint_as_float((unsigned)h << 16);
}
__device__ __forceinline__ void cvt2(float a, float b, uint32& hi, uint32& lo) {
  unsigned short ha = f2bf(a), hb = f2bf(b);
  hi = (uint32)ha | ((uint32)hb << 16);
  lo = (uint32)f2bf(a - bf2f(ha)) | ((uint32)f2bf(b - bf2f(hb)) << 16);
}

__global__ __launch_bounds__(256) void prep_kernel(
    const unsigned char* __restrict__ mraw,
    float* __restrict__ ut, float* __restrict__ mf, u64t* __restrict__ vh,
    const float* __restrict__ Uf, const float* __restrict__ Ub)
{
  int idx = blockIdx.x * 256 + threadIdx.x;
  // transpose U into ut[(d*512+u)*3 + g][k] = U_d[k][g*512+u]
  if (idx < 2*512*3*512) {
    int k = idx & 511;
    int r = idx >> 9;
    int g = r % 3;
    int rest = r / 3;
    int u = rest & 511;
    int dd = rest >> 9;
    const float* Um = dd ? Ub : Uf;
    ut[idx] = Um[k*GG + (g << 9) + u];
  }
  // init versioned h {h=0, tag=0}, both ping-pong buffers (every call: replays!)
  if (idx < 131072)
    __hip_atomic_store(&vh[idx], 0ULL, __ATOMIC_RELAXED, __HIP_MEMORY_SCOPE_AGENT);
  // mask -> float [t][b]; detect bool8 vs int32 storage via byte 1 (mask[0][1] true)
  if (idx < BB*TT) {
    int b = idx / TT, t = idx - b*TT;
    bool bytefmt = (mraw[1] == 1);
    bool mv = bytefmt ? (mraw[idx] != 0) : (((const int*)mraw)[idx] != 0);
    mf[t*BB + b] = mv ? 1.0f : 0.0f;
  }
}

// Wt bf16 hi/lo build: wt[d][n][k] = W_d[k][n], LDS tile transpose, both sides coalesced.
__global__ __launch_bounds__(256) void wt_build(
    const float* __restrict__ Wf, const float* __restrict__ Wb,
    ushort16* __restrict__ wt_hi, ushort16* __restrict__ wt_lo)
{
  __shared__ float tile[64][65];
  const int k0 = blockIdx.x * 64;       // 16
  const int n0 = blockIdx.y * 64;       // 24
  const int d  = blockIdx.z;            // 2
  const float* W = d ? Wb : Wf;
  const int l = threadIdx.x & 63, w = threadIdx.x >> 6;
  #pragma unroll
  for (int j = 0; j < 16; j++) {
    int r = j*4 + w;                    // k-offset
    tile[r][l] = W[(size_t)(k0+r)*GG + n0 + l];     // coalesced (l = n)
  }
  __syncthreads();
  #pragma unroll
  for (int j = 0; j < 16; j++) {
    int r = j*4 + w;                    // n-offset (ug row)
    float f = tile[l][r];               // [k=l][n=r]
    unsigned short h = f2bf(f);
    size_t o = (size_t)(d*GG + n0 + r)*1024 + k0 + l;   // coalesced (l = k)
    wt_hi[o] = h;
    wt_lo[o] = f2bf(f - bf2f(h));
  }
}

// LDS frag read: 8 k-contiguous bf16 at [row][kg*8] of a [128][40]-short array (16B-aligned)
#define LDFRAG(dst, arr, row, kg) do { \
    union { uint4 u; short8v s; } r_; \
    r_.u = *(const uint4*)&arr[(row)*40 + ((kg) << 3)]; \
    dst = r_.s; } while (0)

// XG[t][g][u][b] = X(16000x1024) * W(1024x1536) + bias via bf16x3 MFMA.
// A-operand = Wt rows (ug), B-operand = X rows (m; m-tile = 64 b x 2 t).
__global__ __launch_bounds__(256) void gemm_xg(
    const float* __restrict__ A,
    const ushort16* __restrict__ wt_hi, const ushort16* __restrict__ wt_lo,
    const float* __restrict__ bf, const float* __restrict__ bb,
    float* __restrict__ xgf, float* __restrict__ xgb)
{
  __shared__ __align__(16) ushort16 Ah[128*40];   // [row][32k + 8 pad], 10 KB each
  __shared__ __align__(16) ushort16 Al[128*40];
  __shared__ __align__(16) ushort16 Bh[128*40];
  __shared__ __align__(16) ushort16 Bl[128*40];
  const int tid = threadIdx.x;
  const int l  = tid & 63;
  const int wv = tid >> 6;
  const int wm = wv & 1;                 // m half (t = t0 + wm)
  const int wn = wv >> 1;                // ug half
  const int t0 = blockIdx.x * 2;         // 125
  const int n0 = blockIdx.y * 128;       // 24
  const int d  = (n0 >= GG) ? 1 : 0;
  const int nl0 = n0 - d*GG;
  const float* bias = d ? bb : bf;
  float* xg = d ? xgb : xgf;

  // staging roles: thread -> (row 0..127, k-half 0/16); 16 bf16 = 32 B per half
  const int sr = tid >> 1;
  const int sk = (tid & 1) << 4;
  const ushort16* whp = wt_hi + (size_t)(d*GG + nl0 + sr)*1024 + sk;
  const ushort16* wlp = wt_lo + (size_t)(d*GG + nl0 + sr)*1024 + sk;
  const int mrow = (sr & 63)*TT + t0 + (sr >> 6);
  const float* xp = A + (size_t)mrow*CC + sk;

  f32x4 acc[4][4];
  #pragma unroll
  for (int i = 0; i < 4; i++)
    #pragma unroll
    for (int j = 0; j < 4; j++) acc[i][j] = (f32x4){0.f,0.f,0.f,0.f};

  const int kg = l >> 4;
  for (int k0 = 0; k0 < CC; k0 += 32) {
    // global loads (issue before sync; latency overlaps prev MFMA tail)
    uint4 ha = *(const uint4*)(whp + k0);         // A hi, shorts 0..7
    uint4 hb = *(const uint4*)(whp + k0 + 8);     // A hi, shorts 8..15
    uint4 la = *(const uint4*)(wlp + k0);
    uint4 lb = *(const uint4*)(wlp + k0 + 8);
    float4 x0 = *(const float4*)(xp + k0);
    float4 x1 = *(const float4*)(xp + k0 + 4);
    float4 x2 = *(const float4*)(xp + k0 + 8);
    float4 x3 = *(const float4*)(xp + k0 + 12);
    __syncthreads();                     // prev iter's frag reads done
    {
      *(uint4*)&Ah[sr*40 + sk]     = ha;
      *(uint4*)&Ah[sr*40 + sk + 8] = hb;
      *(uint4*)&Al[sr*40 + sk]     = la;
      *(uint4*)&Al[sr*40 + sk + 8] = lb;
      uint32 bhv[8], blv[8];
      cvt2(x0.x, x0.y, bhv[0], blv[0]); cvt2(x0.z, x0.w, bhv[1], blv[1]);
      cvt2(x1.x, x1.y, bhv[2], blv[2]); cvt2(x1.z, x1.w, bhv[3], blv[3]);
      cvt2(x2.x, x2.y, bhv[4], blv[4]); cvt2(x2.z, x2.w, bhv[5], blv[5]);
      cvt2(x3.x, x3.y, bhv[6], blv[6]); cvt2(x3.z, x3.w, bhv[7], blv[7]);
      *(uint4*)&Bh[sr*40 + sk]     = make_uint4(bhv[0], bhv[1], bhv[2], bhv[3]);
      *(uint4*)&Bh[sr*40 + sk + 8] = make_uint4(bhv[4], bhv[5], bhv[6], bhv[7]);
      *(uint4*)&Bl[sr*40 + sk]     = make_uint4(blv[0], blv[1], blv[2], blv[3]);
      *(uint4*)&Bl[sr*40 + sk + 8] = make_uint4(blv[4], blv[5], blv[6], blv[7]);
    }
    __syncthreads();
    short8v afh[4], afl[4], bfh[4], bfl[4];
    #pragma unroll
    for (int i = 0; i < 4; i++) {
      const int rA = wn*64 + i*16 + (l & 15);
      LDFRAG(afh[i], Ah, rA, kg);
      LDFRAG(afl[i], Al, rA, kg);
      const int rB = wm*64 + i*16 + (l & 15);
      LDFRAG(bfh[i], Bh, rB, kg);
      LDFRAG(bfl[i], Bl, rB, kg);
    }
    #pragma unroll
    for (int i = 0; i < 4; i++)
      #pragma unroll
      for (int j = 0; j < 4; j++) {
        acc[i][j] = __builtin_amdgcn_mfma_f32_16x16x32_bf16(afh[i], bfh[j], acc[i][j], 0, 0, 0);
        acc[i][j] = __builtin_amdgcn_mfma_f32_16x16x32_bf16(afh[i], bfl[j], acc[i][j], 0, 0, 0);
        acc[i][j] = __builtin_amdgcn_mfma_f32_16x16x32_bf16(afl[i], bfh[j], acc[i][j], 0, 0, 0);
      }
  }
  // epilogue: C row = ug (4 consecutive per reg-quad), col = m -> (b, t=t0+wm).
  // Wave store per (i,reg,j): 4 ug-groups x 16 consecutive b = full 64B lines.
  const int t = t0 + wm;
  #pragma unroll
  for (int i = 0; i < 4; i++) {
    const int ugl = wn*64 + i*16 + ((l >> 4) << 2);
    #pragma unroll
    for (int r = 0; r < 4; r++) {
      const int n = nl0 + ugl + r;
      const float bv = bias[n];
      float* orow = xg + (size_t)t*98304 + ((size_t)(n >> 9) << 15) + ((n & 511) << 6);
      #pragma unroll
      for (int j = 0; j < 4; j++)
        orow[j*16 + (l & 15)] = acc[i][j][r] + bv;
    }
  }
}

// Persistent scan via bf16x3 MFMA (unchanged from R8, which passed).
__global__ __launch_bounds__(256, 1) void gru_scan(
    float* xgf, float* xgb,
    const float* __restrict__ ut, const float* __restrict__ bf,
    const float* __restrict__ bb, const float* __restrict__ mf,
    u64t* vh, float* __restrict__ out)
{
  __shared__ __align__(16) unsigned short Bhi[8192];  // [ksub16][b16][kw32] 16 KB
  __shared__ __align__(16) unsigned short Blo[8192];
  const int tid = threadIdx.x;
  const int l   = tid & 63;
  const int wv  = tid >> 6;
  const int bid = blockIdx.x;
  const int d     = bid >> 7;
  const int mb    = (bid >> 2) & 31;     // 32 m-blocks/dir (16 u each)
  const int btile = bid & 3;             // 4 b-tiles (16 b each)

  short8v af_hi[16], af_lo[16];
  {
    const int row = (wv << 4) | (l & 15);
    const int g   = row & 3;
    const int ua  = (mb << 4) | (row >> 2);
    const int kg_ = (l >> 4) << 3;
    if (g < 3) {
      const float* ap = ut + (((size_t)(((d << 9) | ua) * 3 + g)) << 9);
      #pragma unroll
      for (int ks = 0; ks < 16; ks++) {
        #pragma unroll
        for (int j = 0; j < 8; j++) {
          float f = ap[(ks << 5) + kg_ + j];
          unsigned short h = f2bf(f);
          af_hi[ks][j] = (short)h;
          af_lo[ks][j] = (short)f2bf(f - bf2f(h));
        }
      }
    } else {
      #pragma unroll
      for (int ks = 0; ks < 16; ks++)
        #pragma unroll
        for (int j = 0; j < 8; j++) { af_hi[ks][j] = 0; af_lo[ks][j] = 0; }
    }
  }

  const int a  = l >> 4;
  const int u  = (mb << 4) | (wv << 2) | a;
  const int b  = (btile << 4) | (l & 15);
  const float* bias = (d ? bb : bf) + GG;
  const float b1z = bias[u], b1r = bias[512+u], b1h = bias[1024+u];
  float* xg = d ? xgb : xgf;
  float hprev = 0.0f;

  const int kc = tid >> 4;
  const int blw = tid & 15;
  const int cb = (btile << 4) | blw;
  const int boff = ((l & 15) << 6) + (((l >> 4) ^ ((l >> 1) & 3)) << 4);

  const int tf = d ? (TT-1) : 0;
  const float* xp0 = xg + (size_t)tf*98304 + (u << 6) + b;
  float xz = xp0[0], xr = xp0[32768], xh = xp0[65536];
  float m = mf[tf*BB + b];

  for (int s = 0; s < TT; s++) {
    const unsigned us_ = (unsigned)s;
    const int t = d ? (TT-1-s) : s;
    u64t* vin = vh + (size_t)((((unsigned)s & 1u) << 1) | (unsigned)d) * 32768;

    u64t v[32];
    #pragma unroll
    for (int i = 0; i < 32; i++)
      v[i] = __hip_atomic_load(vin + ((kc << 5) + i)*64 + cb, __ATOMIC_RELAXED, __HIP_MEMORY_SCOPE_AGENT);
    while (true) {
      int bad = 0;
      #pragma unroll
      for (int i = 0; i < 32; i++) bad |= ((unsigned)(v[i] >> 32) < us_) ? 1 : 0;
      if (!__any(bad)) break;
      __builtin_amdgcn_s_sleep(1);
      #pragma unroll
      for (int i = 0; i < 32; i++)
        if ((unsigned)(v[i] >> 32) < us_)
          v[i] = __hip_atomic_load(vin + ((kc << 5) + i)*64 + cb, __ATOMIC_RELAXED, __HIP_MEMORY_SCOPE_AGENT);
    }

    __syncthreads();
    #pragma unroll
    for (int q = 0; q < 4; q++) {
      unsigned hv[4], lv[4];
      #pragma unroll
      for (int p = 0; p < 4; p++) {
        float f0 = __uint_as_float((unsigned)v[(q << 3) + (p << 1)]);
        float f1 = __uint_as_float((unsigned)v[(q << 3) + (p << 1) + 1]);
        unsigned short h0 = f2bf(f0), h1 = f2bf(f1);
        hv[p] = (unsigned)h0 | ((unsigned)h1 << 16);
        lv[p] = (unsigned)f2bf(f0 - bf2f(h0)) | ((unsigned)f2bf(f1 - bf2f(h1)) << 16);
      }
      const int phys = q ^ ((blw >> 1) & 3);
      const int off = (kc << 10) + (blw << 6) + (phys << 4);
      *(uint4*)((char*)Bhi + off) = make_uint4(hv[0], hv[1], hv[2], hv[3]);
      *(uint4*)((char*)Blo + off) = make_uint4(lv[0], lv[1], lv[2], lv[3]);
    }
    __syncthreads();

    float xz_n = 0.f, xr_n = 0.f, xh_n = 0.f, m_n = 0.f;
    if (s+1 < TT) {
      const int t2 = d ? (TT-2-s) : (s+1);
      const float* xp = xg + (size_t)t2*98304 + (u << 6) + b;
      xz_n = xp[0]; xr_n = xp[32768]; xh_n = xp[65536];
      m_n  = mf[t2*BB + b];
    }

    f32x4 acc0 = {0.f,0.f,0.f,0.f};
    f32x4 acc1 = {0.f,0.f,0.f,0.f};
    f32x4 acc2 = {0.f,0.f,0.f,0.f};
    #pragma unroll
    for (int ks = 0; ks < 16; ks++) {
      short8v bh  = *(const short8v*)((const char*)Bhi + (ks << 10) + boff);
      short8v bl8 = *(const short8v*)((const char*)Blo + (ks << 10) + boff);
      acc0 = __builtin_amdgcn_mfma_f32_16x16x32_bf16(af_hi[ks], bh,  acc0, 0, 0, 0);
      acc1 = __builtin_amdgcn_mfma_f32_16x16x32_bf16(af_hi[ks], bl8, acc1, 0, 0, 0);
      acc2 = __builtin_amdgcn_mfma_f32_16x16x32_bf16(af_lo[ks], bh,  acc2, 0, 0, 0);
    }
    float az = acc0[0] + acc1[0] + acc2[0];
    float ar = acc0[1] + acc1[1] + acc2[1];
    float ah = acc0[2] + acc1[2] + acc2[2];

    float z  = 1.0f / (1.0f + expf(-(xz + az + b1z)));
    float r  = 1.0f / (1.0f + expf(-(xr + ar + b1r)));
    float cc = tanhf(xh + r * (ah + b1h));
    float hn = z*hprev + (1.0f - z)*cc;
    hn = (m != 0.0f) ? hn : hprev;
    hprev = hn;

    u64t* vout = vh + (size_t)(((((unsigned)s + 1u) & 1u) << 1) | (unsigned)d) * 32768;
    u64t pk = ((u64t)(unsigned)(s+1) << 32) | (u64t)__float_as_uint(hn);
    __hip_atomic_store(&vout[(u << 6) | b], pk, __ATOMIC_RELAXED, __HIP_MEMORY_SCOPE_AGENT);
    xg[(size_t)t*98304 + ((size_t)u << 6) + b] = hn;
    xz = xz_n; xr = xr_n; xh = xh_n; m = m_n;
  }
  out[16384000ull + ((size_t)b << 10) + (d << 9) + u] = hprev;
}

// out[b][t][d*512+u] <- y stored as [t][u][b] inside xg g=0 regions
__global__ __launch_bounds__(256) void y_transpose(
    const float* __restrict__ xgf, const float* __restrict__ xgb,
    float* __restrict__ out)
{
  __shared__ float tile[64][65];
  const int t  = blockIdx.x;
  const int ch = blockIdx.y;
  const int d  = ch >> 3, uc = ch & 7;
  const float* src = (d ? xgb : xgf) + (size_t)t*98304 + (size_t)uc*4096;
  const int lane = threadIdx.x & 63, w = threadIdx.x >> 6;
  #pragma unroll
  for (int j = 0; j < 16; j++) {
    int r = j*4 + w;
    tile[r][lane] = src[r*64 + lane];
  }
  __syncthreads();
  #pragma unroll
  for (int j = 0; j < 16; j++) {
    int b = j*4 + w;
    out[((size_t)b*TT + t)*1024 + (d << 9) + (uc << 6) + lane] = tile[lane][b];
  }
}

extern "C" void kernel_launch(void* const* d_in, const int* in_sizes, int n_in,
                              void* d_out, int out_size, void* d_ws, size_t ws_size,
                              hipStream_t stream) {
  const float* X  = (const float*)d_in[0];
  const unsigned char* Mk = (const unsigned char*)d_in[1];
  const float* Wf = (const float*)d_in[2];
  const float* Uf = (const float*)d_in[3];
  const float* bf = (const float*)d_in[4];
  const float* Wb = (const float*)d_in[5];
  const float* Ub = (const float*)d_in[6];
  const float* bb = (const float*)d_in[7];
  float* out = (float*)d_out;
  float* ws  = (float*)d_ws;
  float* xgf = ws + O_XGF;
  float* xgb = ws + O_XGB;
  float* ut  = ws + O_UT;
  float* mf  = ws + O_MF;
  u64t*  vh  = (u64t*)(ws + O_VH);
  ushort16* wt_hi = (ushort16*)(ws + O_WT);
  ushort16* wt_lo = wt_hi + (size_t)2*GG*1024;

  prep_kernel<<<dim3(6144), dim3(256), 0, stream>>>(Mk, ut, mf, vh, Uf, Ub);
  wt_build<<<dim3(16, 24, 2), dim3(256), 0, stream>>>(Wf, Wb, wt_hi, wt_lo);
  gemm_xg<<<dim3(125, 24), dim3(256), 0, stream>>>(X, wt_hi, wt_lo, bf, bb, xgf, xgb);
  gru_scan<<<dim3(NB), dim3(256), 0, stream>>>(xgf, xgb, ut, bf, bb, mf, vh, out);
  y_transpose<<<dim3(TT, 16), dim3(256), 0, stream>>>(xgf, xgb, out);
}

// Round 11
// 1548.690 us; speedup vs baseline: 6.5897x; 1.1410x over previous
//
#include <hip/hip_runtime.h>
#include <cmath>

#define BB 64
#define TT 250
#define CC 1024
#define GG 1536   // 3U

typedef unsigned long long u64t;
typedef unsigned int uint32;
typedef unsigned short ushort16;
typedef __attribute__((ext_vector_type(8))) short short8v;
typedef __attribute__((ext_vector_type(4))) float f32x4;

// workspace layout (float offsets) — identical to R10
#define O_XGF 0             // [t][g][u][b]; g=0 element (u,b) overwritten by y (same owner thread)
#define O_XGB 24576000      // T*B*G
#define O_UT  49152000      // 2*512*3*512
#define O_MF  50724864      // T*B
#define O_VH  50740864      // u64[2 buf][2 dir][512 u][64 b] = 262,144 float-slots
#define O_WT  51003008      // bf16 Wt: hi[2][1536][1024] + lo[2][1536][1024]

__device__ __forceinline__ unsigned short f2bf(float f) {
  unsigned u = __float_as_uint(f);
  return (unsigned short)((u + 0x7fffu + ((u >> 16) & 1u)) >> 16);   // RNE
}
__device__ __forceinline__ float bf2f(unsigned short h) {
  return __uint_as_float((unsigned)h << 16);
}
__device__ __forceinline__ void cvt2(float a, float b, uint32& hi, uint32& lo) {
  unsigned short ha = f2bf(a), hb = f2bf(b);
  hi = (uint32)ha | ((uint32)hb << 16);
  lo = (uint32)f2bf(a - bf2f(ha)) | ((uint32)f2bf(b - bf2f(hb)) << 16);
}

__global__ __launch_bounds__(256) void prep_kernel(
    const unsigned char* __restrict__ mraw,
    float* __restrict__ ut, float* __restrict__ mf, u64t* __restrict__ vh,
    const float* __restrict__ Uf, const float* __restrict__ Ub)
{
  int idx = blockIdx.x * 256 + threadIdx.x;
  // transpose U into ut[(d*512+u)*3 + g][k] = U_d[k][g*512+u]
  if (idx < 2*512*3*512) {
    int k = idx & 511;
    int r = idx >> 9;
    int g = r % 3;
    int rest = r / 3;
    int u = rest & 511;
    int dd = rest >> 9;
    const float* Um = dd ? Ub : Uf;
    ut[idx] = Um[k*GG + (g << 9) + u];
  }
  // init versioned h {tag=0, hi=0, lo=0}; tag0 = valid step-0 value (h=0)
  if (idx < 131072)
    __hip_atomic_store(&vh[idx], 0ULL, __ATOMIC_RELAXED, __HIP_MEMORY_SCOPE_AGENT);
  // mask -> float [t][b]; detect bool8 vs int32 storage via byte 1 (mask[0][1] true)
  if (idx < BB*TT) {
    int b = idx / TT, t = idx - b*TT;
    bool bytefmt = (mraw[1] == 1);
    bool mv = bytefmt ? (mraw[idx] != 0) : (((const int*)mraw)[idx] != 0);
    mf[t*BB + b] = mv ? 1.0f : 0.0f;
  }
}

// Wt bf16 hi/lo build: wt[d][n][k] = W_d[k][n], LDS tile transpose, both sides coalesced.
__global__ __launch_bounds__(256) void wt_build(
    const float* __restrict__ Wf, const float* __restrict__ Wb,
    ushort16* __restrict__ wt_hi, ushort16* __restrict__ wt_lo)
{
  __shared__ float tile[64][65];
  const int k0 = blockIdx.x * 64;
  const int n0 = blockIdx.y * 64;
  const int d  = blockIdx.z;
  const float* W = d ? Wb : Wf;
  const int l = threadIdx.x & 63, w = threadIdx.x >> 6;
  #pragma unroll
  for (int j = 0; j < 16; j++) {
    int r = j*4 + w;
    tile[r][l] = W[(size_t)(k0+r)*GG + n0 + l];
  }
  __syncthreads();
  #pragma unroll
  for (int j = 0; j < 16; j++) {
    int r = j*4 + w;
    float f = tile[l][r];
    unsigned short h = f2bf(f);
    size_t o = (size_t)(d*GG + n0 + r)*1024 + k0 + l;
    wt_hi[o] = h;
    wt_lo[o] = f2bf(f - bf2f(h));
  }
}

// LDS frag read: 8 k-contiguous bf16 at [row][kg*8] of a [128][40]-short array (16B-aligned)
#define LDFRAG(dst, arr, row, kg) do { \
    union { uint4 u; short8v s; } r_; \
    r_.u = *(const uint4*)&arr[(row)*40 + ((kg) << 3)]; \
    dst = r_.s; } while (0)

// XG[t][g][u][b] = X * W + bias via bf16x3 MFMA (unchanged from R10, which passed).
__global__ __launch_bounds__(256) void gemm_xg(
    const float* __restrict__ A,
    const ushort16* __restrict__ wt_hi, const ushort16* __restrict__ wt_lo,
    const float* __restrict__ bf, const float* __restrict__ bb,
    float* __restrict__ xgf, float* __restrict__ xgb)
{
  __shared__ __align__(16) ushort16 Ah[128*40];
  __shared__ __align__(16) ushort16 Al[128*40];
  __shared__ __align__(16) ushort16 Bh[128*40];
  __shared__ __align__(16) ushort16 Bl[128*40];
  const int tid = threadIdx.x;
  const int l  = tid & 63;
  const int wv = tid >> 6;
  const int wm = wv & 1;
  const int wn = wv >> 1;
  const int t0 = blockIdx.x * 2;
  const int n0 = blockIdx.y * 128;
  const int d  = (n0 >= GG) ? 1 : 0;
  const int nl0 = n0 - d*GG;
  const float* bias = d ? bb : bf;
  float* xg = d ? xgb : xgf;

  const int sr = tid >> 1;
  const int sk = (tid & 1) << 4;
  const ushort16* whp = wt_hi + (size_t)(d*GG + nl0 + sr)*1024 + sk;
  const ushort16* wlp = wt_lo + (size_t)(d*GG + nl0 + sr)*1024 + sk;
  const int mrow = (sr & 63)*TT + t0 + (sr >> 6);
  const float* xp = A + (size_t)mrow*CC + sk;

  f32x4 acc[4][4];
  #pragma unroll
  for (int i = 0; i < 4; i++)
    #pragma unroll
    for (int j = 0; j < 4; j++) acc[i][j] = (f32x4){0.f,0.f,0.f,0.f};

  const int kg = l >> 4;
  for (int k0 = 0; k0 < CC; k0 += 32) {
    uint4 ha = *(const uint4*)(whp + k0);
    uint4 hb = *(const uint4*)(whp + k0 + 8);
    uint4 la = *(const uint4*)(wlp + k0);
    uint4 lb = *(const uint4*)(wlp + k0 + 8);
    float4 x0 = *(const float4*)(xp + k0);
    float4 x1 = *(const float4*)(xp + k0 + 4);
    float4 x2 = *(const float4*)(xp + k0 + 8);
    float4 x3 = *(const float4*)(xp + k0 + 12);
    __syncthreads();
    {
      *(uint4*)&Ah[sr*40 + sk]     = ha;
      *(uint4*)&Ah[sr*40 + sk + 8] = hb;
      *(uint4*)&Al[sr*40 + sk]     = la;
      *(uint4*)&Al[sr*40 + sk + 8] = lb;
      uint32 bhv[8], blv[8];
      cvt2(x0.x, x0.y, bhv[0], blv[0]); cvt2(x0.z, x0.w, bhv[1], blv[1]);
      cvt2(x1.x, x1.y, bhv[2], blv[2]); cvt2(x1.z, x1.w, bhv[3], blv[3]);
      cvt2(x2.x, x2.y, bhv[4], blv[4]); cvt2(x2.z, x2.w, bhv[5], blv[5]);
      cvt2(x3.x, x3.y, bhv[6], blv[6]); cvt2(x3.z, x3.w, bhv[7], blv[7]);
      *(uint4*)&Bh[sr*40 + sk]     = make_uint4(bhv[0], bhv[1], bhv[2], bhv[3]);
      *(uint4*)&Bh[sr*40 + sk + 8] = make_uint4(bhv[4], bhv[5], bhv[6], bhv[7]);
      *(uint4*)&Bl[sr*40 + sk]     = make_uint4(blv[0], blv[1], blv[2], blv[3]);
      *(uint4*)&Bl[sr*40 + sk + 8] = make_uint4(blv[4], blv[5], blv[6], blv[7]);
    }
    __syncthreads();
    short8v afh[4], afl[4], bfh[4], bfl[4];
    #pragma unroll
    for (int i = 0; i < 4; i++) {
      const int rA = wn*64 + i*16 + (l & 15);
      LDFRAG(afh[i], Ah, rA, kg);
      LDFRAG(afl[i], Al, rA, kg);
      const int rB = wm*64 + i*16 + (l & 15);
      LDFRAG(bfh[i], Bh, rB, kg);
      LDFRAG(bfl[i], Bl, rB, kg);
    }
    #pragma unroll
    for (int i = 0; i < 4; i++)
      #pragma unroll
      for (int j = 0; j < 4; j++) {
        acc[i][j] = __builtin_amdgcn_mfma_f32_16x16x32_bf16(afh[i], bfh[j], acc[i][j], 0, 0, 0);
        acc[i][j] = __builtin_amdgcn_mfma_f32_16x16x32_bf16(afh[i], bfl[j], acc[i][j], 0, 0, 0);
        acc[i][j] = __builtin_amdgcn_mfma_f32_16x16x32_bf16(afl[i], bfh[j], acc[i][j], 0, 0, 0);
      }
  }
  const int t = t0 + wm;
  #pragma unroll
  for (int i = 0; i < 4; i++) {
    const int ugl = wn*64 + i*16 + ((l >> 4) << 2);
    #pragma unroll
    for (int r = 0; r < 4; r++) {
      const int n = nl0 + ugl + r;
      const float bv = bias[n];
      float* orow = xg + (size_t)t*98304 + ((size_t)(n >> 9) << 15) + ((n & 511) << 6);
      #pragma unroll
      for (int j = 0; j < 4; j++)
        orow[j*16 + (l & 15)] = acc[i][j][r] + bv;
    }
  }
}

// Persistent scan, bf16x3 MFMA. Block = 32 u x 16 b (512 thr, 8 waves);
// sync group = 16 producers per (d,btile); payload u64 = {tag:32, hi:16, lo:16}
// so consumers repack with bit-ops only (no cvt on the critical path).
__global__ __launch_bounds__(512, 2) void gru_scan(
    float* xgf, float* xgb,
    const float* __restrict__ ut, const float* __restrict__ bf,
    const float* __restrict__ bb, const float* __restrict__ mf,
    u64t* vh, float* __restrict__ out)
{
  __shared__ __align__(16) unsigned short Bhi[8192];  // [ksub16][b16][k32] 16 KB
  __shared__ __align__(16) unsigned short Blo[8192];
  const int tid = threadIdx.x;
  const int l   = tid & 63;
  const int wv  = tid >> 6;              // 0..7
  const int bid = blockIdx.x;
  const int d     = bid >> 6;
  const int mb    = (bid >> 2) & 15;     // 16 m-blocks/dir (32 u each)
  const int btile = bid & 3;             // 4 b-tiles (16 b each)

  // A-frags: wave's 16 rows (4 u x {z,r,h,pad}) of the block's 128-row m-block
  short8v af_hi[16], af_lo[16];
  {
    const int row = (wv << 4) | (l & 15);        // 0..127
    const int g   = row & 3;
    const int ua  = (mb << 5) | (row >> 2);
    const int kg_ = (l >> 4) << 3;
    if (g < 3) {
      const float* ap = ut + (((size_t)(((d << 9) | ua) * 3 + g)) << 9);
      #pragma unroll
      for (int ks = 0; ks < 16; ks++) {
        #pragma unroll
        for (int j = 0; j < 8; j++) {
          float f = ap[(ks << 5) + kg_ + j];
          unsigned short h = f2bf(f);
          af_hi[ks][j] = (short)h;
          af_lo[ks][j] = (short)f2bf(f - bf2f(h));
        }
      }
    } else {
      #pragma unroll
      for (int ks = 0; ks < 16; ks++)
        #pragma unroll
        for (int j = 0; j < 8; j++) { af_hi[ks][j] = 0; af_lo[ks][j] = 0; }
    }
  }

  // output role: u = mb*32 + wv*4 + (l>>4); gate = C reg index; b = col
  const int u  = (mb << 5) | (wv << 2) | (l >> 4);
  const int b  = (btile << 4) | (l & 15);
  const float* bias = (d ? bb : bf) + GG;
  const float b1z = bias[u], b1r = bias[512+u], b1h = bias[1024+u];
  float* xg = d ? xgb : xgf;
  float hprev = 0.0f;

  // staging role: thread (kc = tid>>4, blw = tid&15) owns k = kc*16..+15 at col cb
  const int kc  = tid >> 4;              // 0..31
  const int blw = tid & 15;
  const int cb  = (btile << 4) | blw;
  const int ksub_w = kc >> 1;
  const int qbase  = (kc & 1) << 1;
  const int boff = ((l & 15) << 6) + (((l >> 4) ^ ((l >> 1) & 3)) << 4);

  const int tf = d ? (TT-1) : 0;
  const float* xp0 = xg + (size_t)tf*98304 + (u << 6) + b;
  float xz = xp0[0], xr = xp0[32768], xh = xp0[65536];
  float m = mf[tf*BB + b];

  for (int s = 0; s < TT; s++) {
    const unsigned us_ = (unsigned)s;
    const int t = d ? (TT-1-s) : s;
    u64t* vin = vh + (size_t)((((unsigned)s & 1u) << 1) | (unsigned)d) * 32768;

    // ---- versioned stage (this IS the barrier): 16 u64/thread ----
    u64t v[16];
    #pragma unroll
    for (int i = 0; i < 16; i++)
      v[i] = __hip_atomic_load(vin + ((kc << 4) + i)*64 + cb, __ATOMIC_RELAXED, __HIP_MEMORY_SCOPE_AGENT);
    while (true) {
      int bad = 0;
      #pragma unroll
      for (int i = 0; i < 16; i++) bad |= ((unsigned)(v[i] >> 32) < us_) ? 1 : 0;
      if (!__any(bad)) break;
      __builtin_amdgcn_s_sleep(1);
      #pragma unroll
      for (int i = 0; i < 16; i++)
        if ((unsigned)(v[i] >> 32) < us_)
          v[i] = __hip_atomic_load(vin + ((kc << 4) + i)*64 + cb, __ATOMIC_RELAXED, __HIP_MEMORY_SCOPE_AGENT);
    }

    __syncthreads();     // all waves done reading previous step's B-frags
    // repack bf16 payload -> B-frag rows (pure bit ops)
    #pragma unroll
    for (int half = 0; half < 2; half++) {
      uint32 hw[4], lw[4];
      #pragma unroll
      for (int p = 0; p < 4; p++) {
        u64t v0 = v[(half << 3) + (p << 1)];
        u64t v1 = v[(half << 3) + (p << 1) + 1];
        hw[p] = (uint32)((v0 >> 16) & 0xffffu) | ((uint32)((v1 >> 16) & 0xffffu) << 16);
        lw[p] = (uint32)(v0 & 0xffffu)         | ((uint32)(v1 & 0xffffu) << 16);
      }
      const int phys = (qbase + half) ^ ((blw >> 1) & 3);
      const int off = (ksub_w << 10) + (blw << 6) + (phys << 4);
      *(uint4*)((char*)Bhi + off) = make_uint4(hw[0], hw[1], hw[2], hw[3]);
      *(uint4*)((char*)Blo + off) = make_uint4(lw[0], lw[1], lw[2], lw[3]);
    }
    __syncthreads();     // B ready for all waves

    // prefetch next step's xg/mask; latency hides under MFMA
    float xz_n = 0.f, xr_n = 0.f, xh_n = 0.f, m_n = 0.f;
    if (s+1 < TT) {
      const int t2 = d ? (TT-2-s) : (s+1);
      const float* xp = xg + (size_t)t2*98304 + (u << 6) + b;
      xz_n = xp[0]; xr_n = xp[32768]; xh_n = xp[65536];
      m_n  = mf[t2*BB + b];
    }

    // ---- bf16x3 MFMA: 16 ksub x {hi*hi, hi*lo, lo*hi} ----
    f32x4 acc0 = {0.f,0.f,0.f,0.f};
    f32x4 acc1 = {0.f,0.f,0.f,0.f};
    f32x4 acc2 = {0.f,0.f,0.f,0.f};
    #pragma unroll
    for (int ks = 0; ks < 16; ks++) {
      short8v bh  = *(const short8v*)((const char*)Bhi + (ks << 10) + boff);
      short8v bl8 = *(const short8v*)((const char*)Blo + (ks << 10) + boff);
      acc0 = __builtin_amdgcn_mfma_f32_16x16x32_bf16(af_hi[ks], bh,  acc0, 0, 0, 0);
      acc1 = __builtin_amdgcn_mfma_f32_16x16x32_bf16(af_hi[ks], bl8, acc1, 0, 0, 0);
      acc2 = __builtin_amdgcn_mfma_f32_16x16x32_bf16(af_lo[ks], bh,  acc2, 0, 0, 0);
    }
    float az = acc0[0] + acc1[0] + acc2[0];
    float ar = acc0[1] + acc1[1] + acc2[1];
    float ah = acc0[2] + acc1[2] + acc2[2];

    float z  = 1.0f / (1.0f + expf(-(xz + az + b1z)));
    float r  = 1.0f / (1.0f + expf(-(xr + ar + b1r)));
    float cc = tanhf(xh + r * (ah + b1h));
    float hn = z*hprev + (1.0f - z)*cc;
    hn = (m != 0.0f) ? hn : hprev;
    hprev = hn;

    // publish versioned bf16 h_{s+1}: {tag, hi, lo}
    u64t* vout = vh + (size_t)(((((unsigned)s + 1u) & 1u) << 1) | (unsigned)d) * 32768;
    unsigned short hh = f2bf(hn);
    unsigned short hl = f2bf(hn - bf2f(hh));
    u64t pk = ((u64t)(unsigned)(s+1) << 32) | ((u64t)hh << 16) | (u64t)hl;
    __hip_atomic_store(&vout[(u << 6) | b], pk, __ATOMIC_RELAXED, __HIP_MEMORY_SCOPE_AGENT);
    xg[(size_t)t*98304 + ((size_t)u << 6) + b] = hn;
    xz = xz_n; xr = xr_n; xh = xh_n; m = m_n;
  }
  out[16384000ull + ((size_t)b << 10) + (d << 9) + u] = hprev;
}

// out[b][t][d*512+u] <- y stored as [t][u][b] inside xg g=0 regions
__global__ __launch_bounds__(256) void y_transpose(
    const float* __restrict__ xgf, const float* __restrict__ xgb,
    float* __restrict__ out)
{
  __shared__ float tile[64][65];
  const int t  = blockIdx.x;
  const int ch = blockIdx.y;
  const int d  = ch >> 3, uc = ch & 7;
  const float* src = (d ? xgb : xgf) + (size_t)t*98304 + (size_t)uc*4096;
  const int lane = threadIdx.x & 63, w = threadIdx.x >> 6;
  #pragma unroll
  for (int j = 0; j < 16; j++) {
    int r = j*4 + w;
    tile[r][lane] = src[r*64 + lane];
  }
  __syncthreads();
  #pragma unroll
  for (int j = 0; j < 16; j++) {
    int b = j*4 + w;
    out[((size_t)b*TT + t)*1024 + (d << 9) + (uc << 6) + lane] = tile[lane][b];
  }
}

extern "C" void kernel_launch(void* const* d_in, const int* in_sizes, int n_in,
                              void* d_out, int out_size, void* d_ws, size_t ws_size,
                              hipStream_t stream) {
  const float* X  = (const float*)d_in[0];
  const unsigned char* Mk = (const unsigned char*)d_in[1];
  const float* Wf = (const float*)d_in[2];
  const float* Uf = (const float*)d_in[3];
  const float* bf = (const float*)d_in[4];
  const float* Wb = (const float*)d_in[5];
  const float* Ub = (const float*)d_in[6];
  const float* bb = (const float*)d_in[7];
  float* out = (float*)d_out;
  float* ws  = (float*)d_ws;
  float* xgf = ws + O_XGF;
  float* xgb = ws + O_XGB;
  float* ut  = ws + O_UT;
  float* mf  = ws + O_MF;
  u64t*  vh  = (u64t*)(ws + O_VH);
  ushort16* wt_hi = (ushort16*)(ws + O_WT);
  ushort16* wt_lo = wt_hi + (size_t)2*GG*1024;

  prep_kernel<<<dim3(6144), dim3(256), 0, stream>>>(Mk, ut, mf, vh, Uf, Ub);
  wt_build<<<dim3(16, 24, 2), dim3(256), 0, stream>>>(Wf, Wb, wt_hi, wt_lo);
  gemm_xg<<<dim3(125, 24), dim3(256), 0, stream>>>(X, wt_hi, wt_lo, bf, bb, xgf, xgb);
  gru_scan<<<dim3(128), dim3(512), 0, stream>>>(xgf, xgb, ut, bf, bb, mf, vh, out);
  y_transpose<<<dim3(TT, 16), dim3(256), 0, stream>>>(xgf, xgb, out);
}